// Round 1
// baseline (3030.630 us; speedup 1.0000x reference)
//
#include <hip/hip_runtime.h>

// VariationalGraphSageEncoder: 2-layer GraphSAGE (mean agg) -> (mu, logstd)
//   h  = relu(mean_agg(x) @ W1l + b1 + x @ W1r)           N x 128
//   mu = mean_agg(h) @ Wml + bm + h @ Wmr                 N x 64
//   ls = mean_agg(h) @ Wsl + bs + h @ Wsr                 N x 64
// Shared: cnt (degree) across layers; agg buffer reused; heads fused into one
// 128-col GEMM via packed [Wml|Wsl], [Wmr|Wsr], [bm|bs].

#define IN_C 128

// ---------------- edge-index dtype detection + normalization ----------------
// Harness doc says "integer -> const int*", reference uses int64. Detect:
// for int64 (values < 2^31), every odd 32-bit word of the first 2E words is 0.
__global__ __launch_bounds__(256) void detect_kernel(const int* __restrict__ raw,
                                                     int* __restrict__ flag, int nE) {
    int acc = 0;
    for (long long i = blockIdx.x * 256 + threadIdx.x; i < nE; i += (long long)gridDim.x * 256)
        acc |= raw[2 * i + 1];
    if (acc) atomicOr(flag, 1);
}

__global__ __launch_bounds__(256) void convert_kernel(const int* __restrict__ raw,
                                                      const int* __restrict__ flag,
                                                      int* __restrict__ out, int n2E) {
    int i = blockIdx.x * 256 + threadIdx.x;
    if (i >= n2E) return;
    int f = flag[0];
    out[i] = f ? raw[i] : raw[2 * i];  // f!=0 -> already int32; f==0 -> int64 low words
}

// ---------------- pack layer-2 weights: [Wml|Wsl], [Wmr|Wsr], [bm|bs] -------
__global__ __launch_bounds__(256) void pack_w2_kernel(
    const float* __restrict__ Wml, const float* __restrict__ Wsl,
    const float* __restrict__ Wmr, const float* __restrict__ Wsr,
    const float* __restrict__ bm, const float* __restrict__ bs,
    float* __restrict__ Wcl, float* __restrict__ Wcr, float* __restrict__ bc) {
    int i = blockIdx.x * 256 + threadIdx.x;
    if (i < 128 * 128) {
        int k = i >> 7, c = i & 127;
        Wcl[i] = (c < 64) ? Wml[k * 64 + c] : Wsl[k * 64 + (c - 64)];
        Wcr[i] = (c < 64) ? Wmr[k * 64 + c] : Wsr[k * 64 + (c - 64)];
    }
    if (i < 128) bc[i] = (i < 64) ? bm[i] : bs[i - 64];
}

// ---------------- scatter-add aggregation (one wave per edge) ----------------
__global__ __launch_bounds__(256) void scatter_kernel(
    const float* __restrict__ feat, const int* __restrict__ src,
    const int* __restrict__ dst, float* __restrict__ agg,
    float* __restrict__ cnt, int nE) {
    int gid = blockIdx.x * 256 + threadIdx.x;
    int e = gid >> 6;
    if (e >= nE) return;
    int lane = threadIdx.x & 63;
    int s = src[e];
    int d = dst[e];
    float2 v = reinterpret_cast<const float2*>(feat + (size_t)s * IN_C)[lane];
    float* o = agg + (size_t)d * IN_C + lane * 2;
    atomicAdd(o, v.x);
    atomicAdd(o + 1, v.y);
    if (cnt != nullptr && lane == 0) atomicAdd(cnt + d, 1.0f);
}

// ---------------- fused dual GEMM: out = (agg/cnt)@Wl + A2@Wr + bias ---------
// BM=128 rows/block, BN=128 cols, BK=32, 256 threads, 8x8 thread tile.
// Col mapping per thread: {tx*4..tx*4+3} and {64+tx*4..}, so W-side LDS b128
// reads are contiguous across the 16 tx lanes (conflict-free).
// MODE 0: relu, store h[row*128 + col]
// MODE 1: cols 0..63 -> mu at out[row*64+c]; cols 64..127 -> ls at out[N*64 + row*64 + c]
template <int MODE>
__global__ __launch_bounds__(256) void gemm_kernel(
    const float* __restrict__ A1, const float* __restrict__ cnt,
    const float* __restrict__ A2, const float* __restrict__ Wl,
    const float* __restrict__ Wr, const float* __restrict__ bias,
    float* __restrict__ out, int n) {
    __shared__ float sA1[32][128];
    __shared__ float sA2[32][128];
    __shared__ float sW1[32][128];
    __shared__ float sW2[32][128];

    const int tid = threadIdx.x;
    const int row0 = blockIdx.x * 128;
    const int tx = tid & 15;
    const int ty = tid >> 4;
    const int r_stage = tid & 127;
    const int g_stage = tid >> 7;  // 0/1: which 16-wide k half this thread stages

    float acc[8][8];
#pragma unroll
    for (int i = 0; i < 8; ++i)
#pragma unroll
        for (int j = 0; j < 8; ++j) acc[i][j] = 0.0f;

    const int rowg = row0 + r_stage;
    const bool rok = rowg < n;
    float ic = 1.0f;
    if (rok) ic = 1.0f / fmaxf(cnt[rowg], 1.0f);
    const float* A1g = A1 + (size_t)rowg * 128;
    const float* A2g = A2 + (size_t)rowg * 128;

    for (int kt = 0; kt < 4; ++kt) {
        const int k0 = kt * 32;
        // stage A1 (scaled by 1/cnt) and A2, transposed: sA[k][row]
#pragma unroll
        for (int q = 0; q < 4; ++q) {
            int kk = g_stage * 16 + q * 4;
            float4 v1 = make_float4(0.f, 0.f, 0.f, 0.f);
            float4 v2 = make_float4(0.f, 0.f, 0.f, 0.f);
            if (rok) {
                v1 = *reinterpret_cast<const float4*>(A1g + k0 + kk);
                v2 = *reinterpret_cast<const float4*>(A2g + k0 + kk);
            }
            sA1[kk + 0][r_stage] = v1.x * ic;
            sA1[kk + 1][r_stage] = v1.y * ic;
            sA1[kk + 2][r_stage] = v1.z * ic;
            sA1[kk + 3][r_stage] = v1.w * ic;
            sA2[kk + 0][r_stage] = v2.x;
            sA2[kk + 1][r_stage] = v2.y;
            sA2[kk + 2][r_stage] = v2.z;
            sA2[kk + 3][r_stage] = v2.w;
        }
        // stage W slices, row-major
#pragma unroll
        for (int p = 0; p < 4; ++p) {
            int idx = p * 256 + tid;
            int kk = idx >> 5;
            int c4 = (idx & 31) * 4;
            *reinterpret_cast<float4*>(&sW1[kk][c4]) =
                *reinterpret_cast<const float4*>(Wl + (size_t)(k0 + kk) * 128 + c4);
            *reinterpret_cast<float4*>(&sW2[kk][c4]) =
                *reinterpret_cast<const float4*>(Wr + (size_t)(k0 + kk) * 128 + c4);
        }
        __syncthreads();

#pragma unroll 4
        for (int kk = 0; kk < 32; ++kk) {
            float a1v[8], a2v[8], w1v[8], w2v[8];
            *reinterpret_cast<float4*>(&a1v[0]) = *reinterpret_cast<const float4*>(&sA1[kk][ty * 8]);
            *reinterpret_cast<float4*>(&a1v[4]) = *reinterpret_cast<const float4*>(&sA1[kk][ty * 8 + 4]);
            *reinterpret_cast<float4*>(&a2v[0]) = *reinterpret_cast<const float4*>(&sA2[kk][ty * 8]);
            *reinterpret_cast<float4*>(&a2v[4]) = *reinterpret_cast<const float4*>(&sA2[kk][ty * 8 + 4]);
            *reinterpret_cast<float4*>(&w1v[0]) = *reinterpret_cast<const float4*>(&sW1[kk][tx * 4]);
            *reinterpret_cast<float4*>(&w1v[4]) = *reinterpret_cast<const float4*>(&sW1[kk][64 + tx * 4]);
            *reinterpret_cast<float4*>(&w2v[0]) = *reinterpret_cast<const float4*>(&sW2[kk][tx * 4]);
            *reinterpret_cast<float4*>(&w2v[4]) = *reinterpret_cast<const float4*>(&sW2[kk][64 + tx * 4]);
#pragma unroll
            for (int i = 0; i < 8; ++i)
#pragma unroll
                for (int j = 0; j < 8; ++j)
                    acc[i][j] += a1v[i] * w1v[j] + a2v[i] * w2v[j];
        }
        __syncthreads();
    }

    // epilogue
    float4 b0 = *reinterpret_cast<const float4*>(bias + tx * 4);
    float4 b1v = *reinterpret_cast<const float4*>(bias + 64 + tx * 4);
#pragma unroll
    for (int i = 0; i < 8; ++i) {
        int row = row0 + ty * 8 + i;
        if (row >= n) break;
        float4 o0, o1;
        o0.x = acc[i][0] + b0.x;
        o0.y = acc[i][1] + b0.y;
        o0.z = acc[i][2] + b0.z;
        o0.w = acc[i][3] + b0.w;
        o1.x = acc[i][4] + b1v.x;
        o1.y = acc[i][5] + b1v.y;
        o1.z = acc[i][6] + b1v.z;
        o1.w = acc[i][7] + b1v.w;
        if (MODE == 0) {
            o0.x = fmaxf(o0.x, 0.f); o0.y = fmaxf(o0.y, 0.f);
            o0.z = fmaxf(o0.z, 0.f); o0.w = fmaxf(o0.w, 0.f);
            o1.x = fmaxf(o1.x, 0.f); o1.y = fmaxf(o1.y, 0.f);
            o1.z = fmaxf(o1.z, 0.f); o1.w = fmaxf(o1.w, 0.f);
            *reinterpret_cast<float4*>(out + (size_t)row * 128 + tx * 4) = o0;
            *reinterpret_cast<float4*>(out + (size_t)row * 128 + 64 + tx * 4) = o1;
        } else {
            *reinterpret_cast<float4*>(out + (size_t)row * 64 + tx * 4) = o0;
            *reinterpret_cast<float4*>(out + (size_t)n * 64 + (size_t)row * 64 + tx * 4) = o1;
        }
    }
}

extern "C" void kernel_launch(void* const* d_in, const int* in_sizes, int n_in,
                              void* d_out, int out_size, void* d_ws, size_t ws_size,
                              hipStream_t stream) {
    const float* x = (const float*)d_in[0];
    const int* eidx_raw = (const int*)d_in[1];
    const float* W1l = (const float*)d_in[2];
    const float* b1 = (const float*)d_in[3];
    const float* W1r = (const float*)d_in[4];
    const float* Wml = (const float*)d_in[5];
    const float* bm = (const float*)d_in[6];
    const float* Wmr = (const float*)d_in[7];
    const float* Wsl = (const float*)d_in[8];
    const float* bs = (const float*)d_in[9];
    const float* Wsr = (const float*)d_in[10];
    float* out = (float*)d_out;

    const int n = in_sizes[0] / IN_C;     // 100000
    const int nE = in_sizes[1] / 2;       // 1600000

    // workspace layout (bytes)
    char* ws = (char*)d_ws;
    const size_t cnt_off = 0;                               // n floats
    const size_t flag_off = (size_t)n * 4;                  // 1 int
    const size_t agg_off = (flag_off + 4 + 383) & ~(size_t)383;  // n*128 floats
    const size_t agg_bytes = (size_t)n * 128 * 4;
    const size_t h_off = agg_off + agg_bytes;               // n*128 floats
    const size_t wcl_off = h_off + agg_bytes;               // 128*128 floats
    const size_t wcr_off = wcl_off + 65536;
    const size_t bc_off = wcr_off + 65536;
    const size_t edge_off = (bc_off + 512 + 255) & ~(size_t)255;  // 2E ints

    float* cnt = (float*)(ws + cnt_off);
    int* flag = (int*)(ws + flag_off);
    float* agg = (float*)(ws + agg_off);
    float* h = (float*)(ws + h_off);
    float* Wcl = (float*)(ws + wcl_off);
    float* Wcr = (float*)(ws + wcr_off);
    float* bc = (float*)(ws + bc_off);
    int* edges = (int*)(ws + edge_off);
    const int* src = edges;
    const int* dst = edges + nE;

    // zero cnt + flag + agg in one shot
    hipMemsetAsync(ws, 0, agg_off + agg_bytes, stream);

    // normalize edge_index to int32
    detect_kernel<<<1024, 256, 0, stream>>>(eidx_raw, flag, nE);
    convert_kernel<<<(2 * nE + 255) / 256, 256, 0, stream>>>(eidx_raw, flag, edges, 2 * nE);

    // pack layer-2 weights
    pack_w2_kernel<<<64, 256, 0, stream>>>(Wml, Wsl, Wmr, Wsr, bm, bs, Wcl, Wcr, bc);

    // layer 1: agg = scatter(x), h = relu(agg/cnt @ W1l + b1 + x @ W1r)
    int scatter_blocks = (nE * 64 + 255) / 256;
    scatter_kernel<<<scatter_blocks, 256, 0, stream>>>(x, src, dst, agg, cnt, nE);
    int gemm_blocks = (n + 127) / 128;
    gemm_kernel<0><<<gemm_blocks, 256, 0, stream>>>(agg, cnt, x, W1l, W1r, b1, h, n);

    // layer 2: agg = scatter(h), [mu|ls] = agg/cnt @ [Wml|Wsl] + [bm|bs] + h @ [Wmr|Wsr]
    hipMemsetAsync(ws + agg_off, 0, agg_bytes, stream);
    scatter_kernel<<<scatter_blocks, 256, 0, stream>>>(h, src, dst, agg, nullptr, nE);
    gemm_kernel<1><<<gemm_blocks, 256, 0, stream>>>(agg, cnt, h, Wcl, Wcr, bc, out, n);
}

// Round 2
// 758.104 us; speedup vs baseline: 3.9976x; 3.9976x over previous
//
#include <hip/hip_runtime.h>

// VariationalGraphSageEncoder: 2-layer GraphSAGE (mean agg) -> (mu, logstd)
//   h  = relu(mean_agg(x) @ W1l + b1 + x @ W1r)           N x 128
//   mu = mean_agg(h) @ Wml + bm + h @ Wmr                 N x 64
//   ls = mean_agg(h) @ Wsl + bs + h @ Wsr                 N x 64
// R2: scatter-atomics (1375us each, atomic-latency-bound) -> CSR build once +
// gather-reduce per node (LLC-resident source rows). Heads fused via packed
// [Wml|Wsl] etc. Mean division fused into gather.

#define IN_C 128

// ---------------- edge-index dtype detection + normalization ----------------
__global__ __launch_bounds__(256) void detect_kernel(const int* __restrict__ raw,
                                                     int* __restrict__ flag, int nE) {
    int acc = 0;
    for (long long i = blockIdx.x * 256 + threadIdx.x; i < nE; i += (long long)gridDim.x * 256)
        acc |= raw[2 * i + 1];
    if (acc) atomicOr(flag, 1);
}

__global__ __launch_bounds__(256) void convert_kernel(const int* __restrict__ raw,
                                                      const int* __restrict__ flag,
                                                      int* __restrict__ out, int n2E) {
    int i = blockIdx.x * 256 + threadIdx.x;
    if (i >= n2E) return;
    int f = flag[0];
    out[i] = f ? raw[i] : raw[2 * i];  // f!=0 -> already int32; f==0 -> int64 low words
}

// ---------------- pack layer-2 weights: [Wml|Wsl], [Wmr|Wsr], [bm|bs] -------
__global__ __launch_bounds__(256) void pack_w2_kernel(
    const float* __restrict__ Wml, const float* __restrict__ Wsl,
    const float* __restrict__ Wmr, const float* __restrict__ Wsr,
    const float* __restrict__ bm, const float* __restrict__ bs,
    float* __restrict__ Wcl, float* __restrict__ Wcr, float* __restrict__ bc) {
    int i = blockIdx.x * 256 + threadIdx.x;
    if (i < 128 * 128) {
        int k = i >> 7, c = i & 127;
        Wcl[i] = (c < 64) ? Wml[k * 64 + c] : Wsl[k * 64 + (c - 64)];
        Wcr[i] = (c < 64) ? Wmr[k * 64 + c] : Wsr[k * 64 + (c - 64)];
    }
    if (i < 128) bc[i] = (i < 64) ? bm[i] : bs[i - 64];
}

// ---------------- CSR build -------------------------------------------------
__global__ __launch_bounds__(256) void hist_kernel(const int* __restrict__ dst,
                                                   int* __restrict__ deg, int nE) {
    int e = blockIdx.x * 256 + threadIdx.x;
    if (e < nE) atomicAdd(&deg[dst[e]], 1);
}

// scan1: per-1024-element block exclusive partials (into `partial`) + block sums
__global__ __launch_bounds__(256) void scan1_kernel(const int* __restrict__ deg,
                                                    int* __restrict__ partial,
                                                    int* __restrict__ bsum, int n) {
    __shared__ int s[256];
    const int b = blockIdx.x, t = threadIdx.x;
    const int base = b * 1024;
    int v[4], sum = 0;
#pragma unroll
    for (int q = 0; q < 4; ++q) {
        int i = base + t * 4 + q;
        v[q] = (i < n) ? deg[i] : 0;
        sum += v[q];
    }
    s[t] = sum;
    __syncthreads();
    for (int off = 1; off < 256; off <<= 1) {
        int val = (t >= off) ? s[t - off] : 0;
        __syncthreads();
        s[t] += val;
        __syncthreads();
    }
    int run = s[t] - sum;  // exclusive
#pragma unroll
    for (int q = 0; q < 4; ++q) {
        int i = base + t * 4 + q;
        if (i < n) partial[i] = run;
        run += v[q];
    }
    if (t == 255) bsum[b] = s[255];
}

// scan2: single block scans block sums (nb <= 256)
__global__ __launch_bounds__(256) void scan2_kernel(int* __restrict__ bsum, int nb) {
    __shared__ int s[256];
    const int t = threadIdx.x;
    int v = (t < nb) ? bsum[t] : 0;
    s[t] = v;
    __syncthreads();
    for (int off = 1; off < 256; off <<= 1) {
        int val = (t >= off) ? s[t - off] : 0;
        __syncthreads();
        s[t] += val;
        __syncthreads();
    }
    if (t < nb) bsum[t] = s[t] - v;  // exclusive
}

// scan3: rowptr = partial + bsum[blk]; cursor = rowptr copy for fill
__global__ __launch_bounds__(256) void scan3_kernel(const int* __restrict__ partial,
                                                    const int* __restrict__ bsum,
                                                    int* __restrict__ rowptr,
                                                    int* __restrict__ cursor, int n, int nE) {
    int i = blockIdx.x * 256 + threadIdx.x;
    if (i < n) {
        int v = partial[i] + bsum[i >> 10];
        rowptr[i] = v;
        cursor[i] = v;
    }
    if (i == 0) rowptr[n] = nE;
}

__global__ __launch_bounds__(256) void fill_kernel(const int* __restrict__ src,
                                                   const int* __restrict__ dst,
                                                   int* __restrict__ cursor,
                                                   int* __restrict__ csr, int nE) {
    int e = blockIdx.x * 256 + threadIdx.x;
    if (e >= nE) return;
    int pos = atomicAdd(&cursor[dst[e]], 1);
    csr[pos] = src[e];
}

// ---------------- gather mean-aggregation: one wave per node ----------------
__global__ __launch_bounds__(256) void gather_kernel(const float* __restrict__ feat,
                                                     const int* __restrict__ rowptr,
                                                     const int* __restrict__ csr,
                                                     float* __restrict__ aggm, int n) {
    int w = (blockIdx.x * 256 + threadIdx.x) >> 6;
    if (w >= n) return;
    int lane = threadIdx.x & 63;
    int beg = rowptr[w], end = rowptr[w + 1];
    float ax = 0.f, ay = 0.f, bx = 0.f, by = 0.f;
    int j = beg;
    for (; j + 1 < end; j += 2) {
        int s0 = csr[j], s1 = csr[j + 1];
        float2 v0 = reinterpret_cast<const float2*>(feat + (size_t)s0 * IN_C)[lane];
        float2 v1 = reinterpret_cast<const float2*>(feat + (size_t)s1 * IN_C)[lane];
        ax += v0.x; ay += v0.y;
        bx += v1.x; by += v1.y;
    }
    if (j < end) {
        int s0 = csr[j];
        float2 v0 = reinterpret_cast<const float2*>(feat + (size_t)s0 * IN_C)[lane];
        ax += v0.x; ay += v0.y;
    }
    float ic = 1.0f / fmaxf((float)(end - beg), 1.0f);
    float2 r;
    r.x = (ax + bx) * ic;
    r.y = (ay + by) * ic;
    reinterpret_cast<float2*>(aggm + (size_t)w * IN_C)[lane] = r;
}

// ---------------- fused dual GEMM: out = A1@Wl + A2@Wr + bias ---------------
// BM=128 rows/block, BN=128 cols, BK=32, 256 threads, 8x8 thread tile.
// MODE 0: relu, store h[row*128 + col]
// MODE 1: cols 0..63 -> mu at out[row*64+c]; cols 64..127 -> ls at out[N*64 + row*64 + c]
template <int MODE>
__global__ __launch_bounds__(256) void gemm_kernel(
    const float* __restrict__ A1, const float* __restrict__ A2,
    const float* __restrict__ Wl, const float* __restrict__ Wr,
    const float* __restrict__ bias, float* __restrict__ out, int n) {
    __shared__ float sA1[32][128];
    __shared__ float sA2[32][128];
    __shared__ float sW1[32][128];
    __shared__ float sW2[32][128];

    const int tid = threadIdx.x;
    const int row0 = blockIdx.x * 128;
    const int tx = tid & 15;
    const int ty = tid >> 4;
    const int r_stage = tid & 127;
    const int g_stage = tid >> 7;

    float acc[8][8];
#pragma unroll
    for (int i = 0; i < 8; ++i)
#pragma unroll
        for (int j = 0; j < 8; ++j) acc[i][j] = 0.0f;

    const int rowg = row0 + r_stage;
    const bool rok = rowg < n;
    const float* A1g = A1 + (size_t)rowg * 128;
    const float* A2g = A2 + (size_t)rowg * 128;

    for (int kt = 0; kt < 4; ++kt) {
        const int k0 = kt * 32;
#pragma unroll
        for (int q = 0; q < 4; ++q) {
            int kk = g_stage * 16 + q * 4;
            float4 v1 = make_float4(0.f, 0.f, 0.f, 0.f);
            float4 v2 = make_float4(0.f, 0.f, 0.f, 0.f);
            if (rok) {
                v1 = *reinterpret_cast<const float4*>(A1g + k0 + kk);
                v2 = *reinterpret_cast<const float4*>(A2g + k0 + kk);
            }
            sA1[kk + 0][r_stage] = v1.x;
            sA1[kk + 1][r_stage] = v1.y;
            sA1[kk + 2][r_stage] = v1.z;
            sA1[kk + 3][r_stage] = v1.w;
            sA2[kk + 0][r_stage] = v2.x;
            sA2[kk + 1][r_stage] = v2.y;
            sA2[kk + 2][r_stage] = v2.z;
            sA2[kk + 3][r_stage] = v2.w;
        }
#pragma unroll
        for (int p = 0; p < 4; ++p) {
            int idx = p * 256 + tid;
            int kk = idx >> 5;
            int c4 = (idx & 31) * 4;
            *reinterpret_cast<float4*>(&sW1[kk][c4]) =
                *reinterpret_cast<const float4*>(Wl + (size_t)(k0 + kk) * 128 + c4);
            *reinterpret_cast<float4*>(&sW2[kk][c4]) =
                *reinterpret_cast<const float4*>(Wr + (size_t)(k0 + kk) * 128 + c4);
        }
        __syncthreads();

#pragma unroll 4
        for (int kk = 0; kk < 32; ++kk) {
            float a1v[8], a2v[8], w1v[8], w2v[8];
            *reinterpret_cast<float4*>(&a1v[0]) = *reinterpret_cast<const float4*>(&sA1[kk][ty * 8]);
            *reinterpret_cast<float4*>(&a1v[4]) = *reinterpret_cast<const float4*>(&sA1[kk][ty * 8 + 4]);
            *reinterpret_cast<float4*>(&a2v[0]) = *reinterpret_cast<const float4*>(&sA2[kk][ty * 8]);
            *reinterpret_cast<float4*>(&a2v[4]) = *reinterpret_cast<const float4*>(&sA2[kk][ty * 8 + 4]);
            *reinterpret_cast<float4*>(&w1v[0]) = *reinterpret_cast<const float4*>(&sW1[kk][tx * 4]);
            *reinterpret_cast<float4*>(&w1v[4]) = *reinterpret_cast<const float4*>(&sW1[kk][64 + tx * 4]);
            *reinterpret_cast<float4*>(&w2v[0]) = *reinterpret_cast<const float4*>(&sW2[kk][tx * 4]);
            *reinterpret_cast<float4*>(&w2v[4]) = *reinterpret_cast<const float4*>(&sW2[kk][64 + tx * 4]);
#pragma unroll
            for (int i = 0; i < 8; ++i)
#pragma unroll
                for (int j = 0; j < 8; ++j)
                    acc[i][j] += a1v[i] * w1v[j] + a2v[i] * w2v[j];
        }
        __syncthreads();
    }

    float4 b0 = *reinterpret_cast<const float4*>(bias + tx * 4);
    float4 b1v = *reinterpret_cast<const float4*>(bias + 64 + tx * 4);
#pragma unroll
    for (int i = 0; i < 8; ++i) {
        int row = row0 + ty * 8 + i;
        if (row >= n) break;
        float4 o0, o1;
        o0.x = acc[i][0] + b0.x;
        o0.y = acc[i][1] + b0.y;
        o0.z = acc[i][2] + b0.z;
        o0.w = acc[i][3] + b0.w;
        o1.x = acc[i][4] + b1v.x;
        o1.y = acc[i][5] + b1v.y;
        o1.z = acc[i][6] + b1v.z;
        o1.w = acc[i][7] + b1v.w;
        if (MODE == 0) {
            o0.x = fmaxf(o0.x, 0.f); o0.y = fmaxf(o0.y, 0.f);
            o0.z = fmaxf(o0.z, 0.f); o0.w = fmaxf(o0.w, 0.f);
            o1.x = fmaxf(o1.x, 0.f); o1.y = fmaxf(o1.y, 0.f);
            o1.z = fmaxf(o1.z, 0.f); o1.w = fmaxf(o1.w, 0.f);
            *reinterpret_cast<float4*>(out + (size_t)row * 128 + tx * 4) = o0;
            *reinterpret_cast<float4*>(out + (size_t)row * 128 + 64 + tx * 4) = o1;
        } else {
            *reinterpret_cast<float4*>(out + (size_t)row * 64 + tx * 4) = o0;
            *reinterpret_cast<float4*>(out + (size_t)n * 64 + (size_t)row * 64 + tx * 4) = o1;
        }
    }
}

extern "C" void kernel_launch(void* const* d_in, const int* in_sizes, int n_in,
                              void* d_out, int out_size, void* d_ws, size_t ws_size,
                              hipStream_t stream) {
    const float* x = (const float*)d_in[0];
    const int* eidx_raw = (const int*)d_in[1];
    const float* W1l = (const float*)d_in[2];
    const float* b1 = (const float*)d_in[3];
    const float* W1r = (const float*)d_in[4];
    const float* Wml = (const float*)d_in[5];
    const float* bm = (const float*)d_in[6];
    const float* Wmr = (const float*)d_in[7];
    const float* Wsl = (const float*)d_in[8];
    const float* bs = (const float*)d_in[9];
    const float* Wsr = (const float*)d_in[10];
    float* out = (float*)d_out;

    const int n = in_sizes[0] / IN_C;   // 100000
    const int nE = in_sizes[1] / 2;     // 1600000
    const size_t agg_bytes = (size_t)n * IN_C * 4;

    // ---- workspace layout (bytes). Setup scratch (edges/deg/cursor) is dead
    // after fill_kernel and overlays the aggm region (first written later).
    char* ws = (char*)d_ws;
    const size_t aggm_off = 0;                       // n*128 f32 (51.2 MB)
    //   overlay within aggm region during setup:
    const size_t edge_off = 0;                       // 2E ints (12.8 MB)
    const size_t deg_off = (size_t)2 * nE * 4;       // n ints
    const size_t cur_off = deg_off + (size_t)n * 4;  // n ints
    const size_t h_off = aggm_off + agg_bytes;       // n*128 f32
    const size_t csr_off = h_off + agg_bytes;        // E ints
    const size_t rowptr_off = csr_off + (size_t)nE * 4;  // n+1 ints
    const size_t bsum_off = rowptr_off + (size_t)(n + 1) * 4;  // 256 ints
    const size_t flag_off = bsum_off + 1024;         // 1 int
    const size_t wcl_off = (flag_off + 4 + 255) & ~(size_t)255;
    const size_t wcr_off = wcl_off + 65536;
    const size_t bc_off = wcr_off + 65536;

    float* aggm = (float*)(ws + aggm_off);
    int* edges = (int*)(ws + edge_off);
    int* deg = (int*)(ws + deg_off);
    int* cursor = (int*)(ws + cur_off);
    float* h = (float*)(ws + h_off);
    int* csr = (int*)(ws + csr_off);
    int* rowptr = (int*)(ws + rowptr_off);
    int* bsum = (int*)(ws + bsum_off);
    int* flag = (int*)(ws + flag_off);
    float* Wcl = (float*)(ws + wcl_off);
    float* Wcr = (float*)(ws + wcr_off);
    float* bc = (float*)(ws + bc_off);
    const int* src = edges;
    const int* dst = edges + nE;

    // ---- zero the small per-call state (deg, flag)
    hipMemsetAsync(deg, 0, (size_t)n * 4, stream);
    hipMemsetAsync(flag, 0, 4, stream);

    // ---- normalize edge_index to int32
    detect_kernel<<<1024, 256, 0, stream>>>(eidx_raw, flag, nE);
    convert_kernel<<<(2 * nE + 255) / 256, 256, 0, stream>>>(eidx_raw, flag, edges, 2 * nE);

    // ---- pack layer-2 weights
    pack_w2_kernel<<<64, 256, 0, stream>>>(Wml, Wsl, Wmr, Wsr, bm, bs, Wcl, Wcr, bc);

    // ---- CSR build (once, reused by both layers)
    const int nb = (n + 1023) / 1024;  // <= 256 for n <= 262144
    hist_kernel<<<(nE + 255) / 256, 256, 0, stream>>>(dst, deg, nE);
    scan1_kernel<<<nb, 256, 0, stream>>>(deg, cursor, bsum, n);  // partials into cursor
    scan2_kernel<<<1, 256, 0, stream>>>(bsum, nb);
    scan3_kernel<<<(n + 255) / 256, 256, 0, stream>>>(cursor, bsum, rowptr, cursor, n, nE);
    fill_kernel<<<(nE + 255) / 256, 256, 0, stream>>>(src, dst, cursor, csr, nE);

    // ---- layer 1
    const int gather_blocks = (n * 64 + 255) / 256;
    const int gemm_blocks = (n + 127) / 128;
    gather_kernel<<<gather_blocks, 256, 0, stream>>>(x, rowptr, csr, aggm, n);
    gemm_kernel<0><<<gemm_blocks, 256, 0, stream>>>(aggm, x, W1l, W1r, b1, h, n);

    // ---- layer 2 (fused mu/logstd heads)
    gather_kernel<<<gather_blocks, 256, 0, stream>>>(h, rowptr, csr, aggm, n);
    gemm_kernel<1><<<gemm_blocks, 256, 0, stream>>>(aggm, h, Wcl, Wcr, bc, out, n);
}

// Round 3
// 550.880 us; speedup vs baseline: 5.5014x; 1.3762x over previous
//
#include <hip/hip_runtime.h>

// VariationalGraphSageEncoder: 2-layer GraphSAGE (mean agg) -> (mu, logstd)
// R3: bf16 everywhere (harness compares after bf16 rounding, thr 3.1e-2).
//  - Row layout A[i] = [agg(128) | self(128)] bf16 -> one K=256 MFMA GEMM per
//    layer (heads fused into 128 cols for layer 2).
//  - GEMM: no LDS, no barriers; A-frags direct from global (contiguous in k),
//    B pre-packed into fragment-major 64KB (L2-resident).
//  - Gather: CSR (built once) + per-wave mean over bf16 rows (256B/row).

typedef __attribute__((ext_vector_type(8))) short bf16x8;
typedef __attribute__((ext_vector_type(4))) float f32x4;

__device__ __forceinline__ unsigned short f2bf(float f) {
    unsigned u = __builtin_bit_cast(unsigned, f);
    u += 0x7fff + ((u >> 16) & 1);  // RNE
    return (unsigned short)(u >> 16);
}

// ---------------- edge-index dtype detection + normalization ----------------
__global__ __launch_bounds__(256) void detect_kernel(const int* __restrict__ raw,
                                                     int* __restrict__ flag, int nE) {
    int acc = 0;
    for (long long i = blockIdx.x * 256 + threadIdx.x; i < nE; i += (long long)gridDim.x * 256)
        acc |= raw[2 * i + 1];
    if (acc) atomicOr(flag, 1);
}

__global__ __launch_bounds__(256) void convert_kernel(const int* __restrict__ raw,
                                                      const int* __restrict__ flag,
                                                      int* __restrict__ out, int n2E) {
    int i = blockIdx.x * 256 + threadIdx.x;
    if (i >= n2E) return;
    int f = flag[0];
    out[i] = f ? raw[i] : raw[2 * i];  // int32 passthrough : int64 low words
}

// ---------------- pack weights into fragment-major bf16 ---------------------
// Frag layout (mfma_f32_16x16x32_bf16 B-operand): lane l holds
// B[k = ks*32 + (l>>4)*8 + j][col = nf*16 + (l&15)], j=0..7 contiguous.
// Flat: Bp[(((nf*8 + ks)*64 + l)*8 + j)], nf,ks in [0,8), 32768 elems = 64KB.
__global__ __launch_bounds__(256) void pack_kernel(
    const float* __restrict__ W1l, const float* __restrict__ W1r,
    const float* __restrict__ Wml, const float* __restrict__ Wmr,
    const float* __restrict__ Wsl, const float* __restrict__ Wsr,
    const float* __restrict__ bm, const float* __restrict__ bs,
    unsigned short* __restrict__ B1p, unsigned short* __restrict__ B2p,
    float* __restrict__ bc) {
    int i = blockIdx.x * 256 + threadIdx.x;  // 0..32767
    int j = i & 7, lq = (i >> 3) & 63, ks = (i >> 9) & 7, nf = i >> 12;
    int k = ks * 32 + (lq >> 4) * 8 + j;
    int c = nf * 16 + (lq & 15);
    float w1 = (k < 128) ? W1l[k * 128 + c] : W1r[(k - 128) * 128 + c];
    float w2;
    if (k < 128) w2 = (c < 64) ? Wml[k * 64 + c] : Wsl[k * 64 + (c - 64)];
    else         w2 = (c < 64) ? Wmr[(k - 128) * 64 + c] : Wsr[(k - 128) * 64 + (c - 64)];
    B1p[i] = f2bf(w1);
    B2p[i] = f2bf(w2);
    if (i < 128) bc[i] = (i < 64) ? bm[i] : bs[i - 64];
}

// ---------------- x -> bf16 into A1 self half --------------------------------
__global__ __launch_bounds__(256) void xcvt_kernel(const float* __restrict__ x,
                                                   unsigned short* __restrict__ A1, int total) {
    int i = (blockIdx.x * 256 + threadIdx.x) * 4;
    if (i >= total) return;
    float4 v = *reinterpret_cast<const float4*>(x + i);
    int row = i >> 7, col = i & 127;
    unsigned short* p = A1 + (size_t)row * 256 + 128 + col;
    p[0] = f2bf(v.x); p[1] = f2bf(v.y); p[2] = f2bf(v.z); p[3] = f2bf(v.w);
}

// ---------------- CSR build -------------------------------------------------
__global__ __launch_bounds__(256) void hist_kernel(const int* __restrict__ dst,
                                                   int* __restrict__ deg, int nE) {
    int e = blockIdx.x * 256 + threadIdx.x;
    if (e < nE) atomicAdd(&deg[dst[e]], 1);
}

__global__ __launch_bounds__(256) void scan1_kernel(const int* __restrict__ deg,
                                                    int* __restrict__ partial,
                                                    int* __restrict__ bsum, int n) {
    __shared__ int s[256];
    const int b = blockIdx.x, t = threadIdx.x;
    const int base = b * 1024;
    int v[4], sum = 0;
#pragma unroll
    for (int q = 0; q < 4; ++q) {
        int i = base + t * 4 + q;
        v[q] = (i < n) ? deg[i] : 0;
        sum += v[q];
    }
    s[t] = sum;
    __syncthreads();
    for (int off = 1; off < 256; off <<= 1) {
        int val = (t >= off) ? s[t - off] : 0;
        __syncthreads();
        s[t] += val;
        __syncthreads();
    }
    int run = s[t] - sum;
#pragma unroll
    for (int q = 0; q < 4; ++q) {
        int i = base + t * 4 + q;
        if (i < n) partial[i] = run;
        run += v[q];
    }
    if (t == 255) bsum[b] = s[255];
}

__global__ __launch_bounds__(256) void scan2_kernel(int* __restrict__ bsum, int nb) {
    __shared__ int s[256];
    const int t = threadIdx.x;
    int v = (t < nb) ? bsum[t] : 0;
    s[t] = v;
    __syncthreads();
    for (int off = 1; off < 256; off <<= 1) {
        int val = (t >= off) ? s[t - off] : 0;
        __syncthreads();
        s[t] += val;
        __syncthreads();
    }
    if (t < nb) bsum[t] = s[t] - v;
}

__global__ __launch_bounds__(256) void scan3_kernel(const int* __restrict__ partial,
                                                    const int* __restrict__ bsum,
                                                    int* __restrict__ rowptr,
                                                    int* __restrict__ cursor, int n, int nE) {
    int i = blockIdx.x * 256 + threadIdx.x;
    if (i < n) {
        int v = partial[i] + bsum[i >> 10];
        rowptr[i] = v;
        cursor[i] = v;
    }
    if (i == 0) rowptr[n] = nE;
}

__global__ __launch_bounds__(256) void fill_kernel(const int* __restrict__ src,
                                                   const int* __restrict__ dst,
                                                   int* __restrict__ cursor,
                                                   int* __restrict__ csr, int nE) {
    int e = blockIdx.x * 256 + threadIdx.x;
    if (e >= nE) return;
    int pos = atomicAdd(&cursor[dst[e]], 1);
    csr[pos] = src[e];
}

// ---------------- gather mean-agg over bf16 rows (one wave / node) ----------
// feat/agg viewed as uint (2 bf16 per lane); row stride 128 uints (256 bf16).
__global__ __launch_bounds__(256) void gather_kernel(const unsigned int* __restrict__ feat,
                                                     const int* __restrict__ rowptr,
                                                     const int* __restrict__ csr,
                                                     unsigned int* __restrict__ agg, int n) {
    int wv = (blockIdx.x * 256 + threadIdx.x) >> 6;
    if (wv >= n) return;
    int lane = threadIdx.x & 63;
    int beg = rowptr[wv], end = rowptr[wv + 1];
    float ax = 0.f, ay = 0.f, bx = 0.f, by = 0.f;
    int j = beg;
    for (; j + 1 < end; j += 2) {
        unsigned p0 = feat[(size_t)csr[j] * 128 + lane];
        unsigned p1 = feat[(size_t)csr[j + 1] * 128 + lane];
        ax += __builtin_bit_cast(float, p0 << 16);
        ay += __builtin_bit_cast(float, p0 & 0xffff0000u);
        bx += __builtin_bit_cast(float, p1 << 16);
        by += __builtin_bit_cast(float, p1 & 0xffff0000u);
    }
    if (j < end) {
        unsigned p0 = feat[(size_t)csr[j] * 128 + lane];
        ax += __builtin_bit_cast(float, p0 << 16);
        ay += __builtin_bit_cast(float, p0 & 0xffff0000u);
    }
    float ic = 1.0f / fmaxf((float)(end - beg), 1.0f);
    unsigned r = (unsigned)f2bf((ax + bx) * ic) | ((unsigned)f2bf((ay + by) * ic) << 16);
    agg[(size_t)wv * 128 + lane] = r;
}

// ---------------- MFMA GEMM: out = A(n x 256) @ W(256 x 128) + bias ---------
// 256 thr = 4 waves; wave owns 32 rows x 128 cols = 2x8 frags of 16x16x32.
// A-frag: lane l -> A[row0+mf*16+(l&15)][ks*32+(l>>4)*8 .. +7] (16B contiguous).
// MODE 0: relu -> bf16 into A2 self half (stride 256, offset 128).
// MODE 1: fp32; cols 0..63 -> out[row*64+c]; 64..127 -> out[n*64+row*64+c-64].
template <int MODE>
__global__ __launch_bounds__(256) void mfma_gemm(const unsigned short* __restrict__ A,
                                                 const unsigned short* __restrict__ Bp,
                                                 const float* __restrict__ bias,
                                                 void* __restrict__ outp, int n) {
    const int tid = threadIdx.x;
    const int w = tid >> 6, l = tid & 63;
    const int lr = l & 15;   // row within A-frag / col within B-frag
    const int lg = l >> 4;   // k-group
    const int row0 = blockIdx.x * 128 + w * 32;

    f32x4 acc[2][8];
#pragma unroll
    for (int mf = 0; mf < 2; ++mf)
#pragma unroll
        for (int nf = 0; nf < 8; ++nf) acc[mf][nf] = (f32x4)(0.0f);

    int r0 = row0 + lr;       if (r0 > n - 1) r0 = n - 1;
    int r1 = row0 + 16 + lr;  if (r1 > n - 1) r1 = n - 1;
    const unsigned short* a0p = A + (size_t)r0 * 256 + lg * 8;
    const unsigned short* a1p = A + (size_t)r1 * 256 + lg * 8;
    const unsigned short* bp = Bp + (size_t)l * 8;

    for (int ks = 0; ks < 8; ++ks) {
        bf16x8 a0 = *reinterpret_cast<const bf16x8*>(a0p + ks * 32);
        bf16x8 a1 = *reinterpret_cast<const bf16x8*>(a1p + ks * 32);
#pragma unroll
        for (int nf = 0; nf < 8; ++nf) {
            bf16x8 b = *reinterpret_cast<const bf16x8*>(bp + ((nf * 8 + ks) << 9));
            acc[0][nf] = __builtin_amdgcn_mfma_f32_16x16x32_bf16(a0, b, acc[0][nf], 0, 0, 0);
            acc[1][nf] = __builtin_amdgcn_mfma_f32_16x16x32_bf16(a1, b, acc[1][nf], 0, 0, 0);
        }
    }

    // epilogue: C/D frag layout col = l&15, row = (l>>4)*4 + j  [m89/m91]
    float bv[8];
#pragma unroll
    for (int nf = 0; nf < 8; ++nf) bv[nf] = bias[nf * 16 + lr];

#pragma unroll
    for (int mf = 0; mf < 2; ++mf)
#pragma unroll
        for (int j = 0; j < 4; ++j) {
            int row = row0 + mf * 16 + lg * 4 + j;
            if (row >= n) continue;
#pragma unroll
            for (int nf = 0; nf < 8; ++nf) {
                int col = nf * 16 + lr;
                float v = acc[mf][nf][j] + bv[nf];
                if (MODE == 0) {
                    v = fmaxf(v, 0.0f);
                    ((unsigned short*)outp)[(size_t)row * 256 + 128 + col] = f2bf(v);
                } else {
                    float* o = (float*)outp;
                    if (col < 64) o[(size_t)row * 64 + col] = v;
                    else o[(size_t)n * 64 + (size_t)row * 64 + (col - 64)] = v;
                }
            }
        }
}

extern "C" void kernel_launch(void* const* d_in, const int* in_sizes, int n_in,
                              void* d_out, int out_size, void* d_ws, size_t ws_size,
                              hipStream_t stream) {
    const float* x = (const float*)d_in[0];
    const int* eidx_raw = (const int*)d_in[1];
    const float* W1l = (const float*)d_in[2];
    const float* b1 = (const float*)d_in[3];
    const float* W1r = (const float*)d_in[4];
    const float* Wml = (const float*)d_in[5];
    const float* bm = (const float*)d_in[6];
    const float* Wmr = (const float*)d_in[7];
    const float* Wsl = (const float*)d_in[8];
    const float* bs = (const float*)d_in[9];
    const float* Wsr = (const float*)d_in[10];
    float* out = (float*)d_out;

    const int n = in_sizes[0] / 128;   // 100000
    const int nE = in_sizes[1] / 2;    // 1600000

    // ---- workspace layout (bytes)
    // A1, A2: n x 256 bf16 rows = [agg | self], 51.2 MB each.
    // Setup scratch (edges/deg/cursor, dead after fill) overlays A2 (first
    // written by mfma_gemm<0>, which runs after fill).
    char* ws = (char*)d_ws;
    const size_t a1_off = 0;
    const size_t rowBytes = 512;                     // 256 bf16
    const size_t a_bytes = (size_t)n * rowBytes;
    const size_t a2_off = a1_off + a_bytes;
    const size_t edge_off = a2_off;                  // 2E ints (12.8 MB) overlay
    const size_t deg_off = edge_off + (size_t)2 * nE * 4;
    const size_t cur_off = deg_off + (size_t)n * 4;
    const size_t csr_off = a2_off + a_bytes;         // E ints
    const size_t rowptr_off = csr_off + (size_t)nE * 4;
    const size_t bsum_off = rowptr_off + (size_t)(n + 1) * 4;
    const size_t flag_off = bsum_off + 1024;
    const size_t b1p_off = (flag_off + 4 + 255) & ~(size_t)255;
    const size_t b2p_off = b1p_off + 65536;
    const size_t bc_off = b2p_off + 65536;

    unsigned short* A1 = (unsigned short*)(ws + a1_off);
    unsigned short* A2 = (unsigned short*)(ws + a2_off);
    int* edges = (int*)(ws + edge_off);
    int* deg = (int*)(ws + deg_off);
    int* cursor = (int*)(ws + cur_off);
    int* csr = (int*)(ws + csr_off);
    int* rowptr = (int*)(ws + rowptr_off);
    int* bsum = (int*)(ws + bsum_off);
    int* flag = (int*)(ws + flag_off);
    unsigned short* B1p = (unsigned short*)(ws + b1p_off);
    unsigned short* B2p = (unsigned short*)(ws + b2p_off);
    float* bc = (float*)(ws + bc_off);
    const int* src = edges;
    const int* dst = edges + nE;

    hipMemsetAsync(deg, 0, (size_t)n * 4, stream);
    hipMemsetAsync(flag, 0, 4, stream);

    // edge normalization + weight pack + x conversion
    detect_kernel<<<1024, 256, 0, stream>>>(eidx_raw, flag, nE);
    convert_kernel<<<(2 * nE + 255) / 256, 256, 0, stream>>>(eidx_raw, flag, edges, 2 * nE);
    pack_kernel<<<128, 256, 0, stream>>>(W1l, W1r, Wml, Wmr, Wsl, Wsr, bm, bs, B1p, B2p, bc);
    xcvt_kernel<<<(n * 128 / 4 + 255) / 256, 256, 0, stream>>>(x, A1, n * 128);

    // CSR build (once, reused by both layers)
    const int nb = (n + 1023) / 1024;
    hist_kernel<<<(nE + 255) / 256, 256, 0, stream>>>(dst, deg, nE);
    scan1_kernel<<<nb, 256, 0, stream>>>(deg, cursor, bsum, n);
    scan2_kernel<<<1, 256, 0, stream>>>(bsum, nb);
    scan3_kernel<<<(n + 255) / 256, 256, 0, stream>>>(cursor, bsum, rowptr, cursor, n, nE);
    fill_kernel<<<(nE + 255) / 256, 256, 0, stream>>>(src, dst, cursor, csr, nE);

    const int gather_blocks = (n * 64 + 255) / 256;
    const int gemm_blocks = (n + 127) / 128;

    // layer 1: agg half of A1 <- mean(x_b), then A2 self half <- relu(A1 @ W1 + b1)
    gather_kernel<<<gather_blocks, 256, 0, stream>>>(
        (const unsigned int*)A1 + 64, rowptr, csr, (unsigned int*)A1, n);
    mfma_gemm<0><<<gemm_blocks, 256, 0, stream>>>(A1, B1p, b1, A2, n);

    // layer 2: agg half of A2 <- mean(h), then out <- A2 @ [W2l;W2r] + bc
    gather_kernel<<<gather_blocks, 256, 0, stream>>>(
        (const unsigned int*)A2 + 64, rowptr, csr, (unsigned int*)A2, n);
    mfma_gemm<1><<<gemm_blocks, 256, 0, stream>>>(A2, B2p, bc, out, n);
}

// Round 4
// 423.278 us; speedup vs baseline: 7.1599x; 1.3015x over previous
//
#include <hip/hip_runtime.h>

// VariationalGraphSageEncoder: 2-layer GraphSAGE (mean agg) -> (mu, logstd)
// R4: (a) two-phase LDS-binned CSR build (kills fill_kernel's 105MB random
//     4B-scatter write amplification; folds hist + int64 decode in),
//     (b) gather vectorized to dwordx4: 16 lanes/row, 4 edges in flight,
//     shfl_xor reduce.  bf16 rows [agg(128)|self(128)], MFMA K=256 GEMMs.

typedef __attribute__((ext_vector_type(8))) short bf16x8;
typedef __attribute__((ext_vector_type(4))) float f32x4;

__device__ __forceinline__ unsigned short f2bf(float f) {
    unsigned u = __builtin_bit_cast(unsigned, f);
    u += 0x7fff + ((u >> 16) & 1);  // RNE
    return (unsigned short)(u >> 16);
}
__device__ __forceinline__ float bflo(unsigned u) { return __builtin_bit_cast(float, u << 16); }
__device__ __forceinline__ float bfhi(unsigned u) { return __builtin_bit_cast(float, u & 0xffff0000u); }

// ---------------- edge-index dtype detection ---------------------------------
__global__ __launch_bounds__(256) void detect_kernel(const int* __restrict__ raw,
                                                     int* __restrict__ flag, int nE) {
    int acc = 0;
    for (long long i = blockIdx.x * 256 + threadIdx.x; i < nE; i += (long long)gridDim.x * 256)
        acc |= raw[2 * i + 1];
    if (acc) atomicOr(flag, 1);
}

// ---------------- pack weights into fragment-major bf16 ----------------------
// B-frag (mfma_f32_16x16x32_bf16): lane l holds B[ks*32+(l>>4)*8+j][nf*16+(l&15)]
// Flat: Bp[(((nf*8+ks)*64 + l)*8 + j)], 32768 elems = 64KB.
__global__ __launch_bounds__(256) void pack_kernel(
    const float* __restrict__ W1l, const float* __restrict__ W1r,
    const float* __restrict__ Wml, const float* __restrict__ Wmr,
    const float* __restrict__ Wsl, const float* __restrict__ Wsr,
    const float* __restrict__ bm, const float* __restrict__ bs,
    unsigned short* __restrict__ B1p, unsigned short* __restrict__ B2p,
    float* __restrict__ bc) {
    int i = blockIdx.x * 256 + threadIdx.x;  // 0..32767
    int j = i & 7, lq = (i >> 3) & 63, ks = (i >> 9) & 7, nf = i >> 12;
    int k = ks * 32 + (lq >> 4) * 8 + j;
    int c = nf * 16 + (lq & 15);
    float w1 = (k < 128) ? W1l[k * 128 + c] : W1r[(k - 128) * 128 + c];
    float w2;
    if (k < 128) w2 = (c < 64) ? Wml[k * 64 + c] : Wsl[k * 64 + (c - 64)];
    else         w2 = (c < 64) ? Wmr[(k - 128) * 64 + c] : Wsr[(k - 128) * 64 + (c - 64)];
    B1p[i] = f2bf(w1);
    B2p[i] = f2bf(w2);
    if (i < 128) bc[i] = (i < 64) ? bm[i] : bs[i - 64];
}

// ---------------- x -> bf16 into A1 self half --------------------------------
__global__ __launch_bounds__(256) void xcvt_kernel(const float* __restrict__ x,
                                                   unsigned short* __restrict__ A1, int total) {
    int i = (blockIdx.x * 256 + threadIdx.x) * 4;
    if (i >= total) return;
    float4 v = *reinterpret_cast<const float4*>(x + i);
    int row = i >> 7, col = i & 127;
    unsigned short* p = A1 + (size_t)row * 256 + 128 + col;
    p[0] = f2bf(v.x); p[1] = f2bf(v.y); p[2] = f2bf(v.z); p[3] = f2bf(v.w);
}

// ---------------- CSR build phase A: LDS-binned counting scatter -------------
// Bins (src,dst) 8B records by dst>>shift into per-bucket arrays (dense 8B
// writes), folds deg histogram + int64 decode. NB <= 256 buckets.
__global__ __launch_bounds__(256) void binA_kernel(
    const int* __restrict__ raw, const int* __restrict__ flag,
    int* __restrict__ deg, int* __restrict__ bcnt,
    unsigned long long* __restrict__ recs,
    int nE, int shift, int cap) {
    __shared__ int cnt[256];
    __shared__ int gbase[256];
    const int t = threadIdx.x;
    const bool is64 = (flag[0] == 0);
    for (long long base = (long long)blockIdx.x * 2048; base < nE;
         base += (long long)gridDim.x * 2048) {
        cnt[t] = 0;
        __syncthreads();
        int srcv[8], dstv[8], loff[8], bk[8];
#pragma unroll
        for (int k = 0; k < 8; ++k) {
            long long e = base + t + k * 256;
            bk[k] = -1;
            if (e < nE) {
                int s, d;
                if (is64) { s = raw[2 * e]; d = raw[2 * (nE + e)]; }
                else      { s = raw[e];     d = raw[nE + e]; }
                srcv[k] = s; dstv[k] = d;
                bk[k] = d >> shift;
                loff[k] = atomicAdd(&cnt[bk[k]], 1);
                atomicAdd(&deg[d], 1);
            }
        }
        __syncthreads();
        {
            int c = cnt[t];
            gbase[t] = c ? atomicAdd(&bcnt[t], c) : 0;
        }
        __syncthreads();
#pragma unroll
        for (int k = 0; k < 8; ++k) {
            if (bk[k] >= 0) {
                int pos = gbase[bk[k]] + loff[k];
                if (pos < cap)
                    recs[(size_t)bk[k] * cap + pos] =
                        ((unsigned long long)(unsigned)dstv[k] << 32) | (unsigned)srcv[k];
            }
        }
        __syncthreads();
    }
}

// ---------------- CSR build phase B: per-bucket fill --------------------------
// One block per bucket: cursor slice (~2KB) and csr slice (~32KB) are L2-hot
// and written by exactly this block -> dense downstream writes.
__global__ __launch_bounds__(256) void binB_kernel(
    const unsigned long long* __restrict__ recs, const int* __restrict__ bcnt,
    int* __restrict__ cursor, int* __restrict__ csr, int cap) {
    const int b = blockIdx.x;
    int cnt = bcnt[b];
    if (cnt > cap) cnt = cap;
    const unsigned long long* r = recs + (size_t)b * cap;
    for (int i = threadIdx.x; i < cnt; i += 256) {
        unsigned long long v = r[i];
        int s = (int)(v & 0xffffffffu);
        int d = (int)(v >> 32);
        int pos = atomicAdd(&cursor[d], 1);
        csr[pos] = s;
    }
}

// ---------------- scans: deg -> rowptr (exclusive) ---------------------------
__global__ __launch_bounds__(256) void scan1_kernel(const int* __restrict__ deg,
                                                    int* __restrict__ partial,
                                                    int* __restrict__ bsum, int n) {
    __shared__ int s[256];
    const int b = blockIdx.x, t = threadIdx.x;
    const int base = b * 1024;
    int v[4], sum = 0;
#pragma unroll
    for (int q = 0; q < 4; ++q) {
        int i = base + t * 4 + q;
        v[q] = (i < n) ? deg[i] : 0;
        sum += v[q];
    }
    s[t] = sum;
    __syncthreads();
    for (int off = 1; off < 256; off <<= 1) {
        int val = (t >= off) ? s[t - off] : 0;
        __syncthreads();
        s[t] += val;
        __syncthreads();
    }
    int run = s[t] - sum;
#pragma unroll
    for (int q = 0; q < 4; ++q) {
        int i = base + t * 4 + q;
        if (i < n) partial[i] = run;
        run += v[q];
    }
    if (t == 255) bsum[b] = s[255];
}

__global__ __launch_bounds__(256) void scan2_kernel(int* __restrict__ bsum, int nb) {
    __shared__ int s[256];
    const int t = threadIdx.x;
    int v = (t < nb) ? bsum[t] : 0;
    s[t] = v;
    __syncthreads();
    for (int off = 1; off < 256; off <<= 1) {
        int val = (t >= off) ? s[t - off] : 0;
        __syncthreads();
        s[t] += val;
        __syncthreads();
    }
    if (t < nb) bsum[t] = s[t] - v;
}

__global__ __launch_bounds__(256) void scan3_kernel(const int* __restrict__ partial,
                                                    const int* __restrict__ bsum,
                                                    int* __restrict__ rowptr,
                                                    int* __restrict__ cursor, int n, int nE) {
    int i = blockIdx.x * 256 + threadIdx.x;
    if (i < n) {
        int v = partial[i] + bsum[i >> 10];
        rowptr[i] = v;
        cursor[i] = v;
    }
    if (i == 0) rowptr[n] = nE;
}

// ---------------- gather mean-agg: dwordx4, 4 edges/iter, shfl reduce --------
// feat: row = 64 uints (128 bf16 self half), stride 128 uints.
// lane = eg*16 + c; edge slot eg in [0,4), cols c*4..c*4+3 (uint4 = 16B).
__global__ __launch_bounds__(256) void gather_kernel(const unsigned int* __restrict__ feat,
                                                     const int* __restrict__ rowptr,
                                                     const int* __restrict__ csr,
                                                     unsigned int* __restrict__ agg, int n) {
    int wv = (blockIdx.x * 256 + threadIdx.x) >> 6;
    if (wv >= n) return;
    int lane = threadIdx.x & 63;
    int eg = lane >> 4;
    int c4 = (lane & 15) * 4;
    int beg = rowptr[wv], end = rowptr[wv + 1];
    float acc[8] = {0.f, 0.f, 0.f, 0.f, 0.f, 0.f, 0.f, 0.f};
    for (int jb = beg; jb < end; jb += 4) {
        int e = jb + eg;
        bool ok = e < end;
        int s = csr[ok ? e : beg];
        uint4 v = *reinterpret_cast<const uint4*>(feat + (size_t)s * 128 + c4);
        if (ok) {
            acc[0] += bflo(v.x); acc[1] += bfhi(v.x);
            acc[2] += bflo(v.y); acc[3] += bfhi(v.y);
            acc[4] += bflo(v.z); acc[5] += bfhi(v.z);
            acc[6] += bflo(v.w); acc[7] += bfhi(v.w);
        }
    }
#pragma unroll
    for (int q = 0; q < 8; ++q) {
        acc[q] += __shfl_xor(acc[q], 16);
        acc[q] += __shfl_xor(acc[q], 32);
    }
    if (eg == 0) {
        float ic = 1.0f / fmaxf((float)(end - beg), 1.0f);
        uint4 r;
        r.x = (unsigned)f2bf(acc[0] * ic) | ((unsigned)f2bf(acc[1] * ic) << 16);
        r.y = (unsigned)f2bf(acc[2] * ic) | ((unsigned)f2bf(acc[3] * ic) << 16);
        r.z = (unsigned)f2bf(acc[4] * ic) | ((unsigned)f2bf(acc[5] * ic) << 16);
        r.w = (unsigned)f2bf(acc[6] * ic) | ((unsigned)f2bf(acc[7] * ic) << 16);
        *reinterpret_cast<uint4*>(agg + (size_t)wv * 128 + c4) = r;
    }
}

// ---------------- MFMA GEMM: out = A(n x 256) @ W(256 x 128) + bias ---------
// 4 waves/block; wave owns 32 rows x 128 cols = 2x8 frags of 16x16x32.
// MODE 0: relu -> bf16 self half of A2. MODE 1: fp32 split mu/logstd.
template <int MODE>
__global__ __launch_bounds__(256) void mfma_gemm(const unsigned short* __restrict__ A,
                                                 const unsigned short* __restrict__ Bp,
                                                 const float* __restrict__ bias,
                                                 void* __restrict__ outp, int n) {
    const int tid = threadIdx.x;
    const int w = tid >> 6, l = tid & 63;
    const int lr = l & 15;
    const int lg = l >> 4;
    const int row0 = blockIdx.x * 128 + w * 32;

    f32x4 acc[2][8];
#pragma unroll
    for (int mf = 0; mf < 2; ++mf)
#pragma unroll
        for (int nf = 0; nf < 8; ++nf) acc[mf][nf] = (f32x4)(0.0f);

    int r0 = row0 + lr;       if (r0 > n - 1) r0 = n - 1;
    int r1 = row0 + 16 + lr;  if (r1 > n - 1) r1 = n - 1;
    const unsigned short* a0p = A + (size_t)r0 * 256 + lg * 8;
    const unsigned short* a1p = A + (size_t)r1 * 256 + lg * 8;
    const unsigned short* bp = Bp + (size_t)l * 8;

    for (int ks = 0; ks < 8; ++ks) {
        bf16x8 a0 = *reinterpret_cast<const bf16x8*>(a0p + ks * 32);
        bf16x8 a1 = *reinterpret_cast<const bf16x8*>(a1p + ks * 32);
#pragma unroll
        for (int nf = 0; nf < 8; ++nf) {
            bf16x8 b = *reinterpret_cast<const bf16x8*>(bp + ((nf * 8 + ks) << 9));
            acc[0][nf] = __builtin_amdgcn_mfma_f32_16x16x32_bf16(a0, b, acc[0][nf], 0, 0, 0);
            acc[1][nf] = __builtin_amdgcn_mfma_f32_16x16x32_bf16(a1, b, acc[1][nf], 0, 0, 0);
        }
    }

    float bv[8];
#pragma unroll
    for (int nf = 0; nf < 8; ++nf) bv[nf] = bias[nf * 16 + lr];

#pragma unroll
    for (int mf = 0; mf < 2; ++mf)
#pragma unroll
        for (int j = 0; j < 4; ++j) {
            int row = row0 + mf * 16 + lg * 4 + j;
            if (row >= n) continue;
#pragma unroll
            for (int nf = 0; nf < 8; ++nf) {
                int col = nf * 16 + lr;
                float v = acc[mf][nf][j] + bv[nf];
                if (MODE == 0) {
                    v = fmaxf(v, 0.0f);
                    ((unsigned short*)outp)[(size_t)row * 256 + 128 + col] = f2bf(v);
                } else {
                    float* o = (float*)outp;
                    if (col < 64) o[(size_t)row * 64 + col] = v;
                    else o[(size_t)n * 64 + (size_t)row * 64 + (col - 64)] = v;
                }
            }
        }
}

extern "C" void kernel_launch(void* const* d_in, const int* in_sizes, int n_in,
                              void* d_out, int out_size, void* d_ws, size_t ws_size,
                              hipStream_t stream) {
    const float* x = (const float*)d_in[0];
    const int* eidx_raw = (const int*)d_in[1];
    const float* W1l = (const float*)d_in[2];
    const float* b1 = (const float*)d_in[3];
    const float* W1r = (const float*)d_in[4];
    const float* Wml = (const float*)d_in[5];
    const float* bm = (const float*)d_in[6];
    const float* Wmr = (const float*)d_in[7];
    const float* Wsl = (const float*)d_in[8];
    const float* bs = (const float*)d_in[9];
    const float* Wsr = (const float*)d_in[10];
    float* out = (float*)d_out;

    const int n = in_sizes[0] / 128;   // 100000
    const int nE = in_sizes[1] / 2;    // 1600000

    // bucketing params: NB <= 256 buckets of 2^shift nodes
    int shift = 9;
    while (((n - 1) >> shift) + 1 > 256) ++shift;
    const int NB = ((n - 1) >> shift) + 1;
    long long capll = (((long long)nE << shift) / n) * 5 / 4 + 1024;
    const int cap = (int)((capll + 15) & ~15LL);

    // ---- workspace layout (bytes)
    // A1, A2: n x 256 bf16 = 51.2MB each. recs/deg/cursor overlay A2 (all dead
    // before mfma_gemm<0> first writes A2).
    char* ws = (char*)d_ws;
    const size_t a_bytes = (size_t)n * 512;
    const size_t a1_off = 0;
    const size_t a2_off = a1_off + a_bytes;
    const size_t recs_off = a2_off;                          // NB*cap*8
    const size_t deg_off = recs_off + (size_t)NB * cap * 8;  // n ints
    const size_t cur_off = deg_off + (size_t)n * 4;          // n ints
    const size_t csr_off = a2_off + a_bytes;                 // E ints
    const size_t rowptr_off = csr_off + (size_t)nE * 4;      // n+1 ints
    const size_t bsum_off = rowptr_off + (size_t)(n + 1) * 4;  // 256 ints
    const size_t bcnt_off = bsum_off + 1024;                 // 256 ints
    const size_t flag_off = bcnt_off + 1024;                 // 1 int
    const size_t b1p_off = (flag_off + 4 + 255) & ~(size_t)255;
    const size_t b2p_off = b1p_off + 65536;
    const size_t bc_off = b2p_off + 65536;

    unsigned short* A1 = (unsigned short*)(ws + a1_off);
    unsigned short* A2 = (unsigned short*)(ws + a2_off);
    unsigned long long* recs = (unsigned long long*)(ws + recs_off);
    int* deg = (int*)(ws + deg_off);
    int* cursor = (int*)(ws + cur_off);
    int* csr = (int*)(ws + csr_off);
    int* rowptr = (int*)(ws + rowptr_off);
    int* bsum = (int*)(ws + bsum_off);
    int* bcnt = (int*)(ws + bcnt_off);
    int* flag = (int*)(ws + flag_off);
    unsigned short* B1p = (unsigned short*)(ws + b1p_off);
    unsigned short* B2p = (unsigned short*)(ws + b2p_off);
    float* bc = (float*)(ws + bc_off);

    hipMemsetAsync(deg, 0, (size_t)n * 4, stream);
    hipMemsetAsync(bcnt, 0, 1024 + 4, stream);  // bcnt + flag (contiguous)

    detect_kernel<<<1024, 256, 0, stream>>>(eidx_raw, flag, nE);
    pack_kernel<<<128, 256, 0, stream>>>(W1l, W1r, Wml, Wmr, Wsl, Wsr, bm, bs, B1p, B2p, bc);
    xcvt_kernel<<<(n * 128 / 4 + 255) / 256, 256, 0, stream>>>(x, A1, n * 128);

    // CSR build (binned two-phase; deg histogram folded into phase A)
    binA_kernel<<<256, 256, 0, stream>>>(eidx_raw, flag, deg, bcnt, recs, nE, shift, cap);
    const int nb = (n + 1023) / 1024;
    scan1_kernel<<<nb, 256, 0, stream>>>(deg, cursor, bsum, n);
    scan2_kernel<<<1, 256, 0, stream>>>(bsum, nb);
    scan3_kernel<<<(n + 255) / 256, 256, 0, stream>>>(cursor, bsum, rowptr, cursor, n, nE);
    binB_kernel<<<NB, 256, 0, stream>>>(recs, bcnt, cursor, csr, cap);

    const int gather_blocks = (n * 64 + 255) / 256;
    const int gemm_blocks = (n + 127) / 128;

    // layer 1
    gather_kernel<<<gather_blocks, 256, 0, stream>>>(
        (const unsigned int*)A1 + 64, rowptr, csr, (unsigned int*)A1, n);
    mfma_gemm<0><<<gemm_blocks, 256, 0, stream>>>(A1, B1p, b1, A2, n);

    // layer 2 (fused mu/logstd heads)
    gather_kernel<<<gather_blocks, 256, 0, stream>>>(
        (const unsigned int*)A2 + 64, rowptr, csr, (unsigned int*)A2, n);
    mfma_gemm<1><<<gemm_blocks, 256, 0, stream>>>(A2, B2p, bc, out, n);
}

// Round 5
// 305.917 us; speedup vs baseline: 9.9067x; 1.3836x over previous
//
#include <hip/hip_runtime.h>

// VariationalGraphSageEncoder: 2-layer GraphSAGE (mean agg) -> (mu, logstd)
// R5: CSR build restructured:
//   binA (1 tile/block, grid 1563): decode + LDS-bin (src<<9|ld) 4B records
//        densely per bucket. No deg atomics.
//   bscan: 256-elem exclusive scan of bucket counts.
//   binB (1 block/bucket): LDS deg histogram + LDS scan -> rowptr slice,
//        LDS-cursor fill -> csr slice. All global writes dense & block-owned.
// Gather: 8 edges in flight (2x dwordx4/lane), shfl_xor reduce.
// GEMM: bf16 MFMA K=256 on rows [agg(128)|self(128)], B fragment-major.

typedef __attribute__((ext_vector_type(8))) short bf16x8;
typedef __attribute__((ext_vector_type(4))) float f32x4;

#define SHIFT 9
#define BW 512  // bucket width = 1<<SHIFT; requires n <= 256*BW = 131072

__device__ __forceinline__ unsigned short f2bf(float f) {
    unsigned u = __builtin_bit_cast(unsigned, f);
    u += 0x7fff + ((u >> 16) & 1);  // RNE
    return (unsigned short)(u >> 16);
}
__device__ __forceinline__ float bflo(unsigned u) { return __builtin_bit_cast(float, u << 16); }
__device__ __forceinline__ float bfhi(unsigned u) { return __builtin_bit_cast(float, u & 0xffff0000u); }

// ---------------- edge-index dtype detection (first 64K edges) --------------
__global__ __launch_bounds__(256) void detect_kernel(const int* __restrict__ raw,
                                                     int* __restrict__ flag, int nCheck) {
    int acc = 0;
    for (int i = blockIdx.x * 256 + threadIdx.x; i < nCheck; i += gridDim.x * 256)
        acc |= raw[2 * i + 1];
    if (acc) atomicOr(flag, 1);
}

// ---------------- pack weights into fragment-major bf16 ----------------------
// B-frag (mfma_f32_16x16x32_bf16): lane l holds B[ks*32+(l>>4)*8+j][nf*16+(l&15)]
// Flat: Bp[(((nf*8+ks)*64 + l)*8 + j)], 32768 elems = 64KB.
__global__ __launch_bounds__(256) void pack_kernel(
    const float* __restrict__ W1l, const float* __restrict__ W1r,
    const float* __restrict__ Wml, const float* __restrict__ Wmr,
    const float* __restrict__ Wsl, const float* __restrict__ Wsr,
    const float* __restrict__ bm, const float* __restrict__ bs,
    unsigned short* __restrict__ B1p, unsigned short* __restrict__ B2p,
    float* __restrict__ bc) {
    int i = blockIdx.x * 256 + threadIdx.x;  // 0..32767
    int j = i & 7, lq = (i >> 3) & 63, ks = (i >> 9) & 7, nf = i >> 12;
    int k = ks * 32 + (lq >> 4) * 8 + j;
    int c = nf * 16 + (lq & 15);
    float w1 = (k < 128) ? W1l[k * 128 + c] : W1r[(k - 128) * 128 + c];
    float w2;
    if (k < 128) w2 = (c < 64) ? Wml[k * 64 + c] : Wsl[k * 64 + (c - 64)];
    else         w2 = (c < 64) ? Wmr[(k - 128) * 64 + c] : Wsr[(k - 128) * 64 + (c - 64)];
    B1p[i] = f2bf(w1);
    B2p[i] = f2bf(w2);
    if (i < 128) bc[i] = (i < 64) ? bm[i] : bs[i - 64];
}

// ---------------- x -> bf16 into A1 self half --------------------------------
__global__ __launch_bounds__(256) void xcvt_kernel(const float* __restrict__ x,
                                                   unsigned short* __restrict__ A1, int total) {
    int i = (blockIdx.x * 256 + threadIdx.x) * 4;
    if (i >= total) return;
    float4 v = *reinterpret_cast<const float4*>(x + i);
    int row = i >> 7, col = i & 127;
    unsigned short* p = A1 + (size_t)row * 256 + 128 + col;
    p[0] = f2bf(v.x); p[1] = f2bf(v.y); p[2] = f2bf(v.z); p[3] = f2bf(v.w);
}

// ---------------- CSR build phase A: LDS-binned dense record scatter ---------
// One 1024-edge tile per block. Record = (src << SHIFT) | (dst & (BW-1)),
// binned by dst >> SHIFT into recs[bucket*cap ...] densely.
__global__ __launch_bounds__(256) void binA_kernel(
    const int* __restrict__ raw, const int* __restrict__ flag,
    int* __restrict__ bcnt, unsigned* __restrict__ recs, int nE, int cap) {
    __shared__ int cnt[256];
    __shared__ int gbase[256];
    const int t = threadIdx.x;
    const bool is64 = (flag[0] == 0);
    const long long base = (long long)blockIdx.x * 1024;
    cnt[t] = 0;
    __syncthreads();
    int packv[4], loff[4], bk[4];
#pragma unroll
    for (int k = 0; k < 4; ++k) {
        long long e = base + t + k * 256;
        bk[k] = -1;
        if (e < nE) {
            int s, d;
            if (is64) { s = raw[2 * e]; d = raw[2 * (nE + e)]; }
            else      { s = raw[e];     d = raw[nE + e]; }
            bk[k] = d >> SHIFT;
            packv[k] = (s << SHIFT) | (d & (BW - 1));
            loff[k] = atomicAdd(&cnt[bk[k]], 1);
        }
    }
    __syncthreads();
    {
        int c = cnt[t];
        gbase[t] = c ? atomicAdd(&bcnt[t], c) : 0;
    }
    __syncthreads();
#pragma unroll
    for (int k = 0; k < 4; ++k) {
        if (bk[k] >= 0) {
            int pos = gbase[bk[k]] + loff[k];
            if (pos < cap) recs[(size_t)bk[k] * cap + pos] = (unsigned)packv[k];
        }
    }
}

// ---------------- bucket-count exclusive scan (single block, 256) ------------
__global__ __launch_bounds__(256) void bscan_kernel(const int* __restrict__ bcnt,
                                                    int* __restrict__ bbase) {
    __shared__ int s[256];
    const int t = threadIdx.x;
    int v = bcnt[t];
    s[t] = v;
    __syncthreads();
    for (int off = 1; off < 256; off <<= 1) {
        int val = (t >= off) ? s[t - off] : 0;
        __syncthreads();
        s[t] += val;
        __syncthreads();
    }
    bbase[t] = s[t] - v;
}

// ---------------- CSR build phase B: per-bucket rowptr + fill ----------------
// Block b owns nodes [b*BW, (b+1)*BW): LDS histogram -> LDS scan -> rowptr
// slice (dense), then LDS-cursor fill -> csr slice (block-owned, L2-hot).
__global__ __launch_bounds__(256) void binB_kernel(
    const unsigned* __restrict__ recs, const int* __restrict__ bcnt,
    const int* __restrict__ bbase, int* __restrict__ rowptr,
    int* __restrict__ csr, int cap, int n, int nE) {
    __shared__ int sdeg[BW];
    __shared__ int scur[BW];
    __shared__ int ssum[256];
    const int b = blockIdx.x;
    const int t = threadIdx.x;
    const int node0 = b << SHIFT;
    int cnt = bcnt[b];
    if (cnt > cap) cnt = cap;
    const int base = bbase[b];
    const unsigned* r = recs + (size_t)b * cap;

    sdeg[t] = 0;
    sdeg[t + 256] = 0;
    __syncthreads();
    for (int i = t; i < cnt; i += 256) atomicAdd(&sdeg[r[i] & (BW - 1)], 1);
    __syncthreads();
    // exclusive scan over BW=512 (2 per thread)
    int v0 = sdeg[2 * t], v1 = sdeg[2 * t + 1];
    int sum = v0 + v1;
    ssum[t] = sum;
    __syncthreads();
    for (int off = 1; off < 256; off <<= 1) {
        int val = (t >= off) ? ssum[t - off] : 0;
        __syncthreads();
        ssum[t] += val;
        __syncthreads();
    }
    int ex = ssum[t] - sum;
    scur[2 * t] = ex;
    scur[2 * t + 1] = ex + v0;
    __syncthreads();
    // rowptr slice
#pragma unroll
    for (int q = 0; q < 2; ++q) {
        int i = t + q * 256;
        int node = node0 + i;
        if (node < n) rowptr[node] = base + scur[i];
    }
    if (b == gridDim.x - 1 && t == 0) rowptr[n] = nE;
    __syncthreads();  // rowptr reads of scur complete before fill mutates it
    // fill
    for (int i = t; i < cnt; i += 256) {
        unsigned rec = r[i];
        int pos = base + atomicAdd(&scur[rec & (BW - 1)], 1);
        csr[pos] = (int)(rec >> SHIFT);
    }
}

// ---------------- gather mean-agg: 8 edges in flight, shfl reduce ------------
// feat: row = 64 uints (128 bf16 self half), stride 128 uints.
// lane = eg*16 + c; edge slot eg in [0,4), cols c*4..c*4+3 (uint4 = 16B).
__global__ __launch_bounds__(256) void gather_kernel(const unsigned int* __restrict__ feat,
                                                     const int* __restrict__ rowptr,
                                                     const int* __restrict__ csr,
                                                     unsigned int* __restrict__ agg, int n) {
    int wv = (blockIdx.x * 256 + threadIdx.x) >> 6;
    if (wv >= n) return;
    int lane = threadIdx.x & 63;
    int eg = lane >> 4;
    int c4 = (lane & 15) * 4;
    int beg = rowptr[wv], end = rowptr[wv + 1];
    float acc[8] = {0.f, 0.f, 0.f, 0.f, 0.f, 0.f, 0.f, 0.f};
    int jb = beg;
    for (; jb + 8 <= end; jb += 8) {
        int s0 = csr[jb + eg];
        int s1 = csr[jb + 4 + eg];
        uint4 v0 = *reinterpret_cast<const uint4*>(feat + (size_t)s0 * 128 + c4);
        uint4 v1 = *reinterpret_cast<const uint4*>(feat + (size_t)s1 * 128 + c4);
        acc[0] += bflo(v0.x); acc[1] += bfhi(v0.x);
        acc[2] += bflo(v0.y); acc[3] += bfhi(v0.y);
        acc[4] += bflo(v0.z); acc[5] += bfhi(v0.z);
        acc[6] += bflo(v0.w); acc[7] += bfhi(v0.w);
        acc[0] += bflo(v1.x); acc[1] += bfhi(v1.x);
        acc[2] += bflo(v1.y); acc[3] += bfhi(v1.y);
        acc[4] += bflo(v1.z); acc[5] += bfhi(v1.z);
        acc[6] += bflo(v1.w); acc[7] += bfhi(v1.w);
    }
    for (; jb < end; jb += 4) {
        int e = jb + eg;
        bool ok = e < end;
        int s = csr[ok ? e : beg];
        uint4 v = *reinterpret_cast<const uint4*>(feat + (size_t)s * 128 + c4);
        if (ok) {
            acc[0] += bflo(v.x); acc[1] += bfhi(v.x);
            acc[2] += bflo(v.y); acc[3] += bfhi(v.y);
            acc[4] += bflo(v.z); acc[5] += bfhi(v.z);
            acc[6] += bflo(v.w); acc[7] += bfhi(v.w);
        }
    }
#pragma unroll
    for (int q = 0; q < 8; ++q) {
        acc[q] += __shfl_xor(acc[q], 16);
        acc[q] += __shfl_xor(acc[q], 32);
    }
    if (eg == 0) {
        float ic = 1.0f / fmaxf((float)(end - beg), 1.0f);
        uint4 r;
        r.x = (unsigned)f2bf(acc[0] * ic) | ((unsigned)f2bf(acc[1] * ic) << 16);
        r.y = (unsigned)f2bf(acc[2] * ic) | ((unsigned)f2bf(acc[3] * ic) << 16);
        r.z = (unsigned)f2bf(acc[4] * ic) | ((unsigned)f2bf(acc[5] * ic) << 16);
        r.w = (unsigned)f2bf(acc[6] * ic) | ((unsigned)f2bf(acc[7] * ic) << 16);
        *reinterpret_cast<uint4*>(agg + (size_t)wv * 128 + c4) = r;
    }
}

// ---------------- MFMA GEMM: out = A(n x 256) @ W(256 x 128) + bias ---------
// 4 waves/block; wave owns 32 rows x 128 cols = 2x8 frags of 16x16x32.
// MODE 0: relu -> bf16 self half of A2. MODE 1: fp32 split mu/logstd.
template <int MODE>
__global__ __launch_bounds__(256) void mfma_gemm(const unsigned short* __restrict__ A,
                                                 const unsigned short* __restrict__ Bp,
                                                 const float* __restrict__ bias,
                                                 void* __restrict__ outp, int n) {
    const int tid = threadIdx.x;
    const int w = tid >> 6, l = tid & 63;
    const int lr = l & 15;
    const int lg = l >> 4;
    const int row0 = blockIdx.x * 128 + w * 32;

    f32x4 acc[2][8];
#pragma unroll
    for (int mf = 0; mf < 2; ++mf)
#pragma unroll
        for (int nf = 0; nf < 8; ++nf) acc[mf][nf] = (f32x4)(0.0f);

    int r0 = row0 + lr;       if (r0 > n - 1) r0 = n - 1;
    int r1 = row0 + 16 + lr;  if (r1 > n - 1) r1 = n - 1;
    const unsigned short* a0p = A + (size_t)r0 * 256 + lg * 8;
    const unsigned short* a1p = A + (size_t)r1 * 256 + lg * 8;
    const unsigned short* bp = Bp + (size_t)l * 8;

    for (int ks = 0; ks < 8; ++ks) {
        bf16x8 a0 = *reinterpret_cast<const bf16x8*>(a0p + ks * 32);
        bf16x8 a1 = *reinterpret_cast<const bf16x8*>(a1p + ks * 32);
#pragma unroll
        for (int nf = 0; nf < 8; ++nf) {
            bf16x8 b = *reinterpret_cast<const bf16x8*>(bp + ((nf * 8 + ks) << 9));
            acc[0][nf] = __builtin_amdgcn_mfma_f32_16x16x32_bf16(a0, b, acc[0][nf], 0, 0, 0);
            acc[1][nf] = __builtin_amdgcn_mfma_f32_16x16x32_bf16(a1, b, acc[1][nf], 0, 0, 0);
        }
    }

    float bv[8];
#pragma unroll
    for (int nf = 0; nf < 8; ++nf) bv[nf] = bias[nf * 16 + lr];

#pragma unroll
    for (int mf = 0; mf < 2; ++mf)
#pragma unroll
        for (int j = 0; j < 4; ++j) {
            int row = row0 + mf * 16 + lg * 4 + j;
            if (row >= n) continue;
#pragma unroll
            for (int nf = 0; nf < 8; ++nf) {
                int col = nf * 16 + lr;
                float v = acc[mf][nf][j] + bv[nf];
                if (MODE == 0) {
                    v = fmaxf(v, 0.0f);
                    ((unsigned short*)outp)[(size_t)row * 256 + 128 + col] = f2bf(v);
                } else {
                    float* o = (float*)outp;
                    if (col < 64) o[(size_t)row * 64 + col] = v;
                    else o[(size_t)n * 64 + (size_t)row * 64 + (col - 64)] = v;
                }
            }
        }
}

extern "C" void kernel_launch(void* const* d_in, const int* in_sizes, int n_in,
                              void* d_out, int out_size, void* d_ws, size_t ws_size,
                              hipStream_t stream) {
    const float* x = (const float*)d_in[0];
    const int* eidx_raw = (const int*)d_in[1];
    const float* W1l = (const float*)d_in[2];
    const float* b1 = (const float*)d_in[3];
    const float* W1r = (const float*)d_in[4];
    const float* Wml = (const float*)d_in[5];
    const float* bm = (const float*)d_in[6];
    const float* Wmr = (const float*)d_in[7];
    const float* Wsl = (const float*)d_in[8];
    const float* bs = (const float*)d_in[9];
    const float* Wsr = (const float*)d_in[10];
    float* out = (float*)d_out;

    const int n = in_sizes[0] / 128;   // 100000 (<= 131072 for BW=512, NB<=256)
    const int nE = in_sizes[1] / 2;    // 1600000

    const int NB = ((n - 1) >> SHIFT) + 1;  // 196
    long long capll = (((long long)nE << SHIFT) / n) * 5 / 4 + 1024;
    const int cap = (int)((capll + 15) & ~15LL);

    // ---- workspace layout (bytes)
    // A1, A2: n x 256 bf16 = 51.2MB each. recs (NB*cap*4 ~ 8.8MB) overlays A2
    // (dead before mfma_gemm<0> writes A2).
    char* ws = (char*)d_ws;
    const size_t a_bytes = (size_t)n * 512;
    const size_t a1_off = 0;
    const size_t a2_off = a1_off + a_bytes;
    const size_t recs_off = a2_off;
    const size_t csr_off = a2_off + a_bytes;                 // E ints
    const size_t rowptr_off = csr_off + (size_t)nE * 4;      // n+1 ints
    const size_t bcnt_off = rowptr_off + (size_t)(n + 1) * 4;  // 256 ints
    const size_t flag_off = bcnt_off + 1024;                 // 1 int (memset w/ bcnt)
    const size_t bbase_off = flag_off + 4;                   // 256 ints
    const size_t b1p_off = (bbase_off + 1024 + 255) & ~(size_t)255;
    const size_t b2p_off = b1p_off + 65536;
    const size_t bc_off = b2p_off + 65536;

    unsigned short* A1 = (unsigned short*)(ws + a1_off);
    unsigned short* A2 = (unsigned short*)(ws + a2_off);
    unsigned* recs = (unsigned*)(ws + recs_off);
    int* csr = (int*)(ws + csr_off);
    int* rowptr = (int*)(ws + rowptr_off);
    int* bcnt = (int*)(ws + bcnt_off);
    int* flag = (int*)(ws + flag_off);
    int* bbase = (int*)(ws + bbase_off);
    unsigned short* B1p = (unsigned short*)(ws + b1p_off);
    unsigned short* B2p = (unsigned short*)(ws + b2p_off);
    float* bc = (float*)(ws + bc_off);

    hipMemsetAsync(bcnt, 0, 1024 + 4, stream);  // bcnt + flag

    const int nCheck = nE < 65536 ? nE : 65536;
    detect_kernel<<<64, 256, 0, stream>>>(eidx_raw, flag, nCheck);
    pack_kernel<<<128, 256, 0, stream>>>(W1l, W1r, Wml, Wmr, Wsl, Wsr, bm, bs, B1p, B2p, bc);
    xcvt_kernel<<<(n * 128 / 4 + 255) / 256, 256, 0, stream>>>(x, A1, n * 128);

    // CSR build
    binA_kernel<<<(nE + 1023) / 1024, 256, 0, stream>>>(eidx_raw, flag, bcnt, recs, nE, cap);
    bscan_kernel<<<1, 256, 0, stream>>>(bcnt, bbase);
    binB_kernel<<<NB, 256, 0, stream>>>(recs, bcnt, bbase, rowptr, csr, cap, n, nE);

    const int gather_blocks = (n * 64 + 255) / 256;
    const int gemm_blocks = (n + 127) / 128;

    // layer 1
    gather_kernel<<<gather_blocks, 256, 0, stream>>>(
        (const unsigned int*)A1 + 64, rowptr, csr, (unsigned int*)A1, n);
    mfma_gemm<0><<<gemm_blocks, 256, 0, stream>>>(A1, B1p, b1, A2, n);

    // layer 2 (fused mu/logstd heads)
    gather_kernel<<<gather_blocks, 256, 0, stream>>>(
        (const unsigned int*)A2 + 64, rowptr, csr, (unsigned int*)A2, n);
    mfma_gemm<1><<<gemm_blocks, 256, 0, stream>>>(A2, B2p, bc, out, n);
}

// Round 6
// 287.855 us; speedup vs baseline: 10.5283x; 1.0627x over previous
//
#include <hip/hip_runtime.h>

// VariationalGraphSageEncoder: 2-layer GraphSAGE (mean agg) -> (mu, logstd)
// R6: padded CSR (deg rounded to x4, dummy idx n -> zero row) => branch-free
//     2-deep pipelined gather with v_pk_add_f32 (f32x2) accumulate;
//     prep kernel fuses detect+pack+xcvt+zero; bscan folded into binB.
// GEMM: bf16 MFMA K=256 on rows [agg(128)|self(128)], B fragment-major.

typedef __attribute__((ext_vector_type(8))) short bf16x8;
typedef __attribute__((ext_vector_type(4))) float f32x4;
typedef __attribute__((ext_vector_type(2))) float f32x2;

#define SHIFT 9
#define BW 512  // bucket width; requires n <= 256*BW = 131072

__device__ __forceinline__ unsigned short f2bf(float f) {
    unsigned u = __builtin_bit_cast(unsigned, f);
    u += 0x7fff + ((u >> 16) & 1);  // RNE
    return (unsigned short)(u >> 16);
}
__device__ __forceinline__ float bflo(unsigned u) { return __builtin_bit_cast(float, u << 16); }
__device__ __forceinline__ float bfhi(unsigned u) { return __builtin_bit_cast(float, u & 0xffff0000u); }

// ---------------- prep: detect + pack weights + x->bf16 + zero dummy row ----
// blocks [0,nXB): xcvt; [nXB,nXB+64): detect; [nXB+64,nXB+192): pack;
// nXB+192: zero row n self-halves of A1/A2.
__global__ __launch_bounds__(256) void prep_kernel(
    const float* __restrict__ x, const int* __restrict__ raw, int* __restrict__ flag,
    const float* __restrict__ W1l, const float* __restrict__ W1r,
    const float* __restrict__ Wml, const float* __restrict__ Wmr,
    const float* __restrict__ Wsl, const float* __restrict__ Wsr,
    const float* __restrict__ bm, const float* __restrict__ bs,
    unsigned short* __restrict__ B1p, unsigned short* __restrict__ B2p,
    float* __restrict__ bc, unsigned short* __restrict__ A1,
    unsigned short* __restrict__ A2, int n, int nE, int nXB) {
    const int b = blockIdx.x;
    const int t = threadIdx.x;
    if (b < nXB) {
        int i = (b * 256 + t) * 4;
        if (i < n * 128) {
            float4 v = *reinterpret_cast<const float4*>(x + i);
            int row = i >> 7, col = i & 127;
            unsigned short* p = A1 + (size_t)row * 256 + 128 + col;
            p[0] = f2bf(v.x); p[1] = f2bf(v.y); p[2] = f2bf(v.z); p[3] = f2bf(v.w);
        }
    } else if (b < nXB + 64) {
        const int nCheck = nE < 65536 ? nE : 65536;
        int acc = 0;
        for (int i = (b - nXB) * 256 + t; i < nCheck; i += 64 * 256)
            acc |= raw[2 * i + 1];
        if (acc) atomicOr(flag, 1);
    } else if (b < nXB + 192) {
        // B-frag (mfma 16x16x32 bf16): lane l holds B[ks*32+(l>>4)*8+j][nf*16+(l&15)]
        int i = (b - nXB - 64) * 256 + t;  // 0..32767
        int j = i & 7, lq = (i >> 3) & 63, ks = (i >> 9) & 7, nf = i >> 12;
        int k = ks * 32 + (lq >> 4) * 8 + j;
        int c = nf * 16 + (lq & 15);
        float w1 = (k < 128) ? W1l[k * 128 + c] : W1r[(k - 128) * 128 + c];
        float w2;
        if (k < 128) w2 = (c < 64) ? Wml[k * 64 + c] : Wsl[k * 64 + (c - 64)];
        else         w2 = (c < 64) ? Wmr[(k - 128) * 64 + c] : Wsr[(k - 128) * 64 + (c - 64)];
        B1p[i] = f2bf(w1);
        B2p[i] = f2bf(w2);
        if (i < 128) bc[i] = (i < 64) ? bm[i] : bs[i - 64];
    } else {
        if (t < 64) {
            ((unsigned*)A1)[(size_t)n * 128 + 64 + t] = 0;
            ((unsigned*)A2)[(size_t)n * 128 + 64 + t] = 0;
        }
    }
}

// ---------------- CSR build phase A: LDS-binned dense record scatter ---------
// One 1024-edge tile per block. Record = (src << SHIFT) | (dst & (BW-1)).
__global__ __launch_bounds__(256) void binA_kernel(
    const int* __restrict__ raw, const int* __restrict__ flag,
    int* __restrict__ bcnt, unsigned* __restrict__ recs, int nE, int cap) {
    __shared__ int cnt[256];
    __shared__ int gbase[256];
    const int t = threadIdx.x;
    const bool is64 = (flag[0] == 0);
    const long long base = (long long)blockIdx.x * 1024;
    cnt[t] = 0;
    __syncthreads();
    int packv[4], loff[4], bk[4];
#pragma unroll
    for (int k = 0; k < 4; ++k) {
        long long e = base + t + k * 256;
        bk[k] = -1;
        if (e < nE) {
            int s, d;
            if (is64) { s = raw[2 * e]; d = raw[2 * (nE + e)]; }
            else      { s = raw[e];     d = raw[nE + e]; }
            bk[k] = d >> SHIFT;
            packv[k] = (s << SHIFT) | (d & (BW - 1));
            loff[k] = atomicAdd(&cnt[bk[k]], 1);
        }
    }
    __syncthreads();
    {
        int c = cnt[t];
        gbase[t] = c ? atomicAdd(&bcnt[t], c) : 0;
    }
    __syncthreads();
#pragma unroll
    for (int k = 0; k < 4; ++k) {
        if (bk[k] >= 0) {
            int pos = gbase[bk[k]] + loff[k];
            if (pos < cap) recs[(size_t)bk[k] * cap + pos] = (unsigned)packv[k];
        }
    }
}

// ---------------- CSR build phase B: per-bucket padded rowptr + fill ---------
// Block b owns nodes [b*BW,(b+1)*BW). Scans bcnt itself (bscan folded in);
// bucket base gets +b*3*BW margin so per-node x4 padding never overflows.
// Pads each node's list to a multiple of 4 with dummy index n (zero row).
__global__ __launch_bounds__(256) void binB_kernel(
    const unsigned* __restrict__ recs, const int* __restrict__ bcnt,
    int* __restrict__ rowptrP, int* __restrict__ cnts,
    int* __restrict__ csr, int cap, int n, int NB) {
    __shared__ int sdeg[BW];
    __shared__ int scur[BW];
    __shared__ int ssum[256];
    const int b = blockIdx.x;
    const int t = threadIdx.x;
    const int node0 = b << SHIFT;

    // fold bscan: inclusive scan of raw bucket counts
    int rawb = (t < NB) ? bcnt[t] : 0;
    ssum[t] = rawb;
    __syncthreads();
    for (int off = 1; off < 256; off <<= 1) {
        int val = (t >= off) ? ssum[t - off] : 0;
        __syncthreads();
        ssum[t] += val;
        __syncthreads();
    }
    const int base = ((b == 0) ? 0 : ssum[b - 1]) + b * 3 * BW;
    int cnt = bcnt[b];
    if (cnt > cap) cnt = cap;
    const unsigned* r = recs + (size_t)b * cap;
    __syncthreads();

    // local degree histogram
    sdeg[t] = 0;
    sdeg[t + 256] = 0;
    __syncthreads();
    for (int i = t; i < cnt; i += 256) atomicAdd(&sdeg[r[i] & (BW - 1)], 1);
    __syncthreads();
    // exclusive scan of PADDED degrees (2 nodes/thread)
    int d0 = sdeg[2 * t], d1 = sdeg[2 * t + 1];
    int p0 = (d0 + 3) & ~3, p1 = (d1 + 3) & ~3;
    int sum = p0 + p1;
    ssum[t] = sum;
    __syncthreads();
    for (int off = 1; off < 256; off <<= 1) {
        int val = (t >= off) ? ssum[t - off] : 0;
        __syncthreads();
        ssum[t] += val;
        __syncthreads();
    }
    int ex = ssum[t] - sum;
    scur[2 * t] = ex;
    scur[2 * t + 1] = ex + p0;
    __syncthreads();
    // rowptrP + true counts
#pragma unroll
    for (int q = 0; q < 2; ++q) {
        int i = 2 * t + q;  // node-local index; scur[i] = padded exclusive prefix
        int node = node0 + i;
        if (node < n) {
            rowptrP[node] = base + scur[i];
            cnts[node] = sdeg[i];
        }
    }
    __syncthreads();
    // fill real edges (scur becomes cursor)
    for (int i = t; i < cnt; i += 256) {
        unsigned rec = r[i];
        int pos = base + atomicAdd(&scur[rec & (BW - 1)], 1);
        csr[pos] = (int)(rec >> SHIFT);
    }
    __syncthreads();
    // fill pads with dummy index n
#pragma unroll
    for (int q = 0; q < 2; ++q) {
        int i = 2 * t + q;
        int node = node0 + i;
        if (node < n) {
            int d = sdeg[i];
            int pad = (4 - (d & 3)) & 3;
            int st = base + scur[i];  // = base + ex_i + d_i
            for (int k = 0; k < pad; ++k) csr[st + k] = n;
        }
    }
}

// ---------------- gather mean-agg: branch-free, 2-deep pipeline, pk_add -----
// feat: self half rows, stride 128 uints; dummy row n is zeros.
// lane = eg*16 + c; edge slot eg in [0,4), cols c*4..c*4+3 (uint4 = 16B).
__global__ __launch_bounds__(256) void gather_kernel(const unsigned int* __restrict__ feat,
                                                     const int* __restrict__ rowptrP,
                                                     const int* __restrict__ cnts,
                                                     const int* __restrict__ csr,
                                                     unsigned int* __restrict__ agg, int n) {
    int wv = (blockIdx.x * 256 + threadIdx.x) >> 6;
    if (wv >= n) return;
    int lane = threadIdx.x & 63;
    int eg = lane >> 4;
    int c4 = (lane & 15) * 4;
    int beg = rowptrP[wv];
    int deg = cnts[wv];
    int endp = beg + ((deg + 3) & ~3);
    f32x2 a0 = (f32x2)(0.f), a1 = (f32x2)(0.f), a2 = (f32x2)(0.f), a3 = (f32x2)(0.f);
    int jb = beg;
    if (jb < endp) {
        int s = csr[jb + eg];
        uint4 v = *reinterpret_cast<const uint4*>(feat + (size_t)s * 128 + c4);
#pragma unroll 2
        for (jb += 4; jb < endp; jb += 4) {
            int s2 = csr[jb + eg];
            uint4 v2 = *reinterpret_cast<const uint4*>(feat + (size_t)s2 * 128 + c4);
            a0 += (f32x2){bflo(v.x), bfhi(v.x)};
            a1 += (f32x2){bflo(v.y), bfhi(v.y)};
            a2 += (f32x2){bflo(v.z), bfhi(v.z)};
            a3 += (f32x2){bflo(v.w), bfhi(v.w)};
            v = v2;
        }
        a0 += (f32x2){bflo(v.x), bfhi(v.x)};
        a1 += (f32x2){bflo(v.y), bfhi(v.y)};
        a2 += (f32x2){bflo(v.z), bfhi(v.z)};
        a3 += (f32x2){bflo(v.w), bfhi(v.w)};
    }
    float acc[8] = {a0.x, a0.y, a1.x, a1.y, a2.x, a2.y, a3.x, a3.y};
#pragma unroll
    for (int q = 0; q < 8; ++q) {
        acc[q] += __shfl_xor(acc[q], 16);
        acc[q] += __shfl_xor(acc[q], 32);
    }
    if (eg == 0) {
        float ic = 1.0f / fmaxf((float)deg, 1.0f);
        uint4 r;
        r.x = (unsigned)f2bf(acc[0] * ic) | ((unsigned)f2bf(acc[1] * ic) << 16);
        r.y = (unsigned)f2bf(acc[2] * ic) | ((unsigned)f2bf(acc[3] * ic) << 16);
        r.z = (unsigned)f2bf(acc[4] * ic) | ((unsigned)f2bf(acc[5] * ic) << 16);
        r.w = (unsigned)f2bf(acc[6] * ic) | ((unsigned)f2bf(acc[7] * ic) << 16);
        *reinterpret_cast<uint4*>(agg + (size_t)wv * 128 + c4) = r;
    }
}

// ---------------- MFMA GEMM: out = A(n x 256) @ W(256 x 128) + bias ---------
// 4 waves/block; wave owns 32 rows x 128 cols = 2x8 frags of 16x16x32.
// MODE 0: relu -> bf16 self half of A2. MODE 1: fp32 split mu/logstd.
template <int MODE>
__global__ __launch_bounds__(256) void mfma_gemm(const unsigned short* __restrict__ A,
                                                 const unsigned short* __restrict__ Bp,
                                                 const float* __restrict__ bias,
                                                 void* __restrict__ outp, int n) {
    const int tid = threadIdx.x;
    const int w = tid >> 6, l = tid & 63;
    const int lr = l & 15;
    const int lg = l >> 4;
    const int row0 = blockIdx.x * 128 + w * 32;

    f32x4 acc[2][8];
#pragma unroll
    for (int mf = 0; mf < 2; ++mf)
#pragma unroll
        for (int nf = 0; nf < 8; ++nf) acc[mf][nf] = (f32x4)(0.0f);

    int r0 = row0 + lr;       if (r0 > n - 1) r0 = n - 1;
    int r1 = row0 + 16 + lr;  if (r1 > n - 1) r1 = n - 1;
    const unsigned short* a0p = A + (size_t)r0 * 256 + lg * 8;
    const unsigned short* a1p = A + (size_t)r1 * 256 + lg * 8;
    const unsigned short* bp = Bp + (size_t)l * 8;

    for (int ks = 0; ks < 8; ++ks) {
        bf16x8 a0 = *reinterpret_cast<const bf16x8*>(a0p + ks * 32);
        bf16x8 a1 = *reinterpret_cast<const bf16x8*>(a1p + ks * 32);
#pragma unroll
        for (int nf = 0; nf < 8; ++nf) {
            bf16x8 b = *reinterpret_cast<const bf16x8*>(bp + ((nf * 8 + ks) << 9));
            acc[0][nf] = __builtin_amdgcn_mfma_f32_16x16x32_bf16(a0, b, acc[0][nf], 0, 0, 0);
            acc[1][nf] = __builtin_amdgcn_mfma_f32_16x16x32_bf16(a1, b, acc[1][nf], 0, 0, 0);
        }
    }

    float bv[8];
#pragma unroll
    for (int nf = 0; nf < 8; ++nf) bv[nf] = bias[nf * 16 + lr];

#pragma unroll
    for (int mf = 0; mf < 2; ++mf)
#pragma unroll
        for (int j = 0; j < 4; ++j) {
            int row = row0 + mf * 16 + lg * 4 + j;
            if (row >= n) continue;
#pragma unroll
            for (int nf = 0; nf < 8; ++nf) {
                int col = nf * 16 + lr;
                float v = acc[mf][nf][j] + bv[nf];
                if (MODE == 0) {
                    v = fmaxf(v, 0.0f);
                    ((unsigned short*)outp)[(size_t)row * 256 + 128 + col] = f2bf(v);
                } else {
                    float* o = (float*)outp;
                    if (col < 64) o[(size_t)row * 64 + col] = v;
                    else o[(size_t)n * 64 + (size_t)row * 64 + (col - 64)] = v;
                }
            }
        }
}

extern "C" void kernel_launch(void* const* d_in, const int* in_sizes, int n_in,
                              void* d_out, int out_size, void* d_ws, size_t ws_size,
                              hipStream_t stream) {
    const float* x = (const float*)d_in[0];
    const int* eidx_raw = (const int*)d_in[1];
    const float* W1l = (const float*)d_in[2];
    const float* b1 = (const float*)d_in[3];
    const float* W1r = (const float*)d_in[4];
    const float* Wml = (const float*)d_in[5];
    const float* bm = (const float*)d_in[6];
    const float* Wmr = (const float*)d_in[7];
    const float* Wsl = (const float*)d_in[8];
    const float* bs = (const float*)d_in[9];
    const float* Wsr = (const float*)d_in[10];
    float* out = (float*)d_out;

    const int n = in_sizes[0] / 128;   // 100000 (<= 131072)
    const int nE = in_sizes[1] / 2;    // 1600000

    const int NB = ((n - 1) >> SHIFT) + 1;  // 196
    long long capll = (((long long)nE << SHIFT) / n) * 5 / 4 + 1024;
    const int cap = (int)((capll + 15) & ~15LL);
    const int csr_ints = nE + NB * 3 * BW + 64;

    // ---- workspace layout (bytes); A1/A2 have n+1 rows (row n = zero dummy).
    // recs (~9MB) overlays A2 (dead before mfma_gemm<0> writes A2 rows < n;
    // prep's zeroing of A2 row n is beyond the recs region).
    char* ws = (char*)d_ws;
    const size_t a_bytes = (size_t)(n + 1) * 512;
    const size_t a1_off = 0;
    const size_t a2_off = a1_off + a_bytes;
    const size_t recs_off = a2_off;
    const size_t csr_off = a2_off + a_bytes;
    const size_t rowptr_off = csr_off + (size_t)csr_ints * 4;   // n ints
    const size_t cnts_off = rowptr_off + (size_t)n * 4;         // n ints
    const size_t bcnt_off = cnts_off + (size_t)n * 4;           // 256 ints
    const size_t flag_off = bcnt_off + 1024;                    // 1 int
    const size_t b1p_off = (flag_off + 4 + 255) & ~(size_t)255;
    const size_t b2p_off = b1p_off + 65536;
    const size_t bc_off = b2p_off + 65536;

    unsigned short* A1 = (unsigned short*)(ws + a1_off);
    unsigned short* A2 = (unsigned short*)(ws + a2_off);
    unsigned* recs = (unsigned*)(ws + recs_off);
    int* csr = (int*)(ws + csr_off);
    int* rowptrP = (int*)(ws + rowptr_off);
    int* cnts = (int*)(ws + cnts_off);
    int* bcnt = (int*)(ws + bcnt_off);
    int* flag = (int*)(ws + flag_off);
    unsigned short* B1p = (unsigned short*)(ws + b1p_off);
    unsigned short* B2p = (unsigned short*)(ws + b2p_off);
    float* bc = (float*)(ws + bc_off);

    hipMemsetAsync(bcnt, 0, 1024 + 4, stream);  // bcnt + flag

    // prep: xcvt + detect + pack + zero dummy rows
    const int nXB = (n * 32 + 255) / 256;  // xcvt blocks (4 floats/thread)
    prep_kernel<<<nXB + 193, 256, 0, stream>>>(x, eidx_raw, flag, W1l, W1r, Wml, Wmr,
                                               Wsl, Wsr, bm, bs, B1p, B2p, bc, A1, A2,
                                               n, nE, nXB);

    // CSR build (padded)
    binA_kernel<<<(nE + 1023) / 1024, 256, 0, stream>>>(eidx_raw, flag, bcnt, recs, nE, cap);
    binB_kernel<<<NB, 256, 0, stream>>>(recs, bcnt, rowptrP, cnts, csr, cap, n, NB);

    const int gather_blocks = (n * 64 + 255) / 256;
    const int gemm_blocks = (n + 127) / 128;

    // layer 1
    gather_kernel<<<gather_blocks, 256, 0, stream>>>(
        (const unsigned int*)A1 + 64, rowptrP, cnts, csr, (unsigned int*)A1, n);
    mfma_gemm<0><<<gemm_blocks, 256, 0, stream>>>(A1, B1p, b1, A2, n);

    // layer 2 (fused mu/logstd heads)
    gather_kernel<<<gather_blocks, 256, 0, stream>>>(
        (const unsigned int*)A2 + 64, rowptrP, cnts, csr, (unsigned int*)A2, n);
    mfma_gemm<1><<<gemm_blocks, 256, 0, stream>>>(A2, B2p, bc, out, n);
}

// Round 7
// 269.025 us; speedup vs baseline: 11.2652x; 1.0700x over previous
//
#include <hip/hip_runtime.h>

// VariationalGraphSageEncoder: 2-layer GraphSAGE (mean agg) -> (mu, logstd)
// R7: stage1 fuses {binA-v2 two-pass dense binning (per-block int64 detect),
//     x->bf16 xcvt, weight pack, dummy-row zero} into one grid (overlapped);
//     gather gets an explicit 2-deep load pipeline.
// GEMM: bf16 MFMA K=256 on rows [agg(128)|self(128)], B fragment-major.

typedef __attribute__((ext_vector_type(8))) short bf16x8;
typedef __attribute__((ext_vector_type(4))) float f32x4;
typedef __attribute__((ext_vector_type(2))) float f32x2;

#define SHIFT 9
#define BW 512  // bucket width; requires n <= 256*BW = 131072

__device__ __forceinline__ unsigned short f2bf(float f) {
    unsigned u = __builtin_bit_cast(unsigned, f);
    u += 0x7fff + ((u >> 16) & 1);  // RNE
    return (unsigned short)(u >> 16);
}
__device__ __forceinline__ float bflo(unsigned u) { return __builtin_bit_cast(float, u << 16); }
__device__ __forceinline__ float bfhi(unsigned u) { return __builtin_bit_cast(float, u & 0xffff0000u); }

// ---------------- stage1: binA + xcvt + pack + zero, disjoint block ranges --
// blocks [0, nBinA): binA-v2 4096-edge tiles (two-pass, per-block is64 detect)
// [nBinA, nBinA+nXB): x -> bf16 self half of A1
// [nBinA+nXB, +128): pack weights fragment-major
// last: zero dummy row n of A1/A2
__global__ __launch_bounds__(256) void stage1_kernel(
    const float* __restrict__ x, const int* __restrict__ raw,
    const float* __restrict__ W1l, const float* __restrict__ W1r,
    const float* __restrict__ Wml, const float* __restrict__ Wmr,
    const float* __restrict__ Wsl, const float* __restrict__ Wsr,
    const float* __restrict__ bm, const float* __restrict__ bs,
    unsigned short* __restrict__ B1p, unsigned short* __restrict__ B2p,
    float* __restrict__ bc, unsigned short* __restrict__ A1,
    unsigned short* __restrict__ A2, int* __restrict__ bcnt,
    unsigned* __restrict__ recs, int n, int nE, int cap, int nBinA, int nXB) {
    const int b = blockIdx.x;
    const int t = threadIdx.x;
    if (b < nBinA) {
        __shared__ int cnt[256];
        __shared__ int cur[256];
        __shared__ int gbase[256];
        __shared__ int sflag;
        const int e0 = b * 4096;
        const int e1 = (e0 + 4096 < nE) ? e0 + 4096 : nE;
        // per-block int64 detection: odd words all zero <=> int64 (ids < 2^31)
        int acc = 0;
        for (int e = e0 + t; e < e1; e += 256) acc |= raw[2 * e + 1];
        if (t == 0) sflag = 0;
        cnt[t] = 0;
        cur[t] = 0;
        __syncthreads();
        if (acc) atomicOr(&sflag, 1);
        __syncthreads();
        const bool is64 = (sflag == 0);
        // pass 1: count per bucket
        for (int e = e0 + t; e < e1; e += 256) {
            int d = is64 ? raw[2 * (nE + e)] : raw[nE + e];
            atomicAdd(&cnt[d >> SHIFT], 1);
        }
        __syncthreads();
        gbase[t] = cnt[t] ? atomicAdd(&bcnt[t], cnt[t]) : 0;
        __syncthreads();
        // pass 2: place records densely per bucket
        for (int e = e0 + t; e < e1; e += 256) {
            int s, d;
            if (is64) { s = raw[2 * e]; d = raw[2 * (nE + e)]; }
            else      { s = raw[e];     d = raw[nE + e]; }
            int bk = d >> SHIFT;
            int pos = gbase[bk] + atomicAdd(&cur[bk], 1);
            if (pos < cap)
                recs[(size_t)bk * cap + pos] = ((unsigned)s << SHIFT) | (unsigned)(d & (BW - 1));
        }
    } else if (b < nBinA + nXB) {
        int i = ((b - nBinA) * 256 + t) * 4;
        if (i < n * 128) {
            float4 v = *reinterpret_cast<const float4*>(x + i);
            int row = i >> 7, col = i & 127;
            unsigned short* p = A1 + (size_t)row * 256 + 128 + col;
            p[0] = f2bf(v.x); p[1] = f2bf(v.y); p[2] = f2bf(v.z); p[3] = f2bf(v.w);
        }
    } else if (b < nBinA + nXB + 128) {
        // B-frag (mfma 16x16x32 bf16): lane l holds B[ks*32+(l>>4)*8+j][nf*16+(l&15)]
        int i = (b - nBinA - nXB) * 256 + t;  // 0..32767
        int j = i & 7, lq = (i >> 3) & 63, ks = (i >> 9) & 7, nf = i >> 12;
        int k = ks * 32 + (lq >> 4) * 8 + j;
        int c = nf * 16 + (lq & 15);
        float w1 = (k < 128) ? W1l[k * 128 + c] : W1r[(k - 128) * 128 + c];
        float w2;
        if (k < 128) w2 = (c < 64) ? Wml[k * 64 + c] : Wsl[k * 64 + (c - 64)];
        else         w2 = (c < 64) ? Wmr[(k - 128) * 64 + c] : Wsr[(k - 128) * 64 + (c - 64)];
        B1p[i] = f2bf(w1);
        B2p[i] = f2bf(w2);
        if (i < 128) bc[i] = (i < 64) ? bm[i] : bs[i - 64];
    } else {
        if (t < 64) {
            ((unsigned*)A1)[(size_t)n * 128 + 64 + t] = 0;
            ((unsigned*)A2)[(size_t)n * 128 + 64 + t] = 0;
        }
    }
}

// ---------------- CSR build phase B: per-bucket padded rowptr + fill ---------
// Block b owns nodes [b*BW,(b+1)*BW). Scans bcnt itself; bucket base gets
// +b*3*BW margin so per-node x4 padding never overflows. Pads each node's
// list to a multiple of 4 with dummy index n (zero feature row).
__global__ __launch_bounds__(256) void binB_kernel(
    const unsigned* __restrict__ recs, const int* __restrict__ bcnt,
    int* __restrict__ rowptrP, int* __restrict__ cnts,
    int* __restrict__ csr, int cap, int n, int NB) {
    __shared__ int sdeg[BW];
    __shared__ int scur[BW];
    __shared__ int ssum[256];
    const int b = blockIdx.x;
    const int t = threadIdx.x;
    const int node0 = b << SHIFT;

    // inclusive scan of raw bucket counts (bscan folded in)
    int rawb = (t < NB) ? bcnt[t] : 0;
    ssum[t] = rawb;
    __syncthreads();
    for (int off = 1; off < 256; off <<= 1) {
        int val = (t >= off) ? ssum[t - off] : 0;
        __syncthreads();
        ssum[t] += val;
        __syncthreads();
    }
    const int base = ((b == 0) ? 0 : ssum[b - 1]) + b * 3 * BW;
    int cnt = bcnt[b];
    if (cnt > cap) cnt = cap;
    const unsigned* r = recs + (size_t)b * cap;
    __syncthreads();

    // local degree histogram
    sdeg[t] = 0;
    sdeg[t + 256] = 0;
    __syncthreads();
    for (int i = t; i < cnt; i += 256) atomicAdd(&sdeg[r[i] & (BW - 1)], 1);
    __syncthreads();
    // exclusive scan of PADDED degrees (2 nodes/thread)
    int d0 = sdeg[2 * t], d1 = sdeg[2 * t + 1];
    int p0 = (d0 + 3) & ~3, p1 = (d1 + 3) & ~3;
    int sum = p0 + p1;
    ssum[t] = sum;
    __syncthreads();
    for (int off = 1; off < 256; off <<= 1) {
        int val = (t >= off) ? ssum[t - off] : 0;
        __syncthreads();
        ssum[t] += val;
        __syncthreads();
    }
    int ex = ssum[t] - sum;
    scur[2 * t] = ex;
    scur[2 * t + 1] = ex + p0;
    __syncthreads();
    // rowptrP + true counts
#pragma unroll
    for (int q = 0; q < 2; ++q) {
        int i = 2 * t + q;
        int node = node0 + i;
        if (node < n) {
            rowptrP[node] = base + scur[i];
            cnts[node] = sdeg[i];
        }
    }
    __syncthreads();
    // fill real edges (scur becomes cursor)
    for (int i = t; i < cnt; i += 256) {
        unsigned rec = r[i];
        int pos = base + atomicAdd(&scur[rec & (BW - 1)], 1);
        csr[pos] = (int)(rec >> SHIFT);
    }
    __syncthreads();
    // fill pads with dummy index n
#pragma unroll
    for (int q = 0; q < 2; ++q) {
        int i = 2 * t + q;
        int node = node0 + i;
        if (node < n) {
            int d = sdeg[i];
            int pad = (4 - (d & 3)) & 3;
            int st = base + scur[i];  // = base + ex_i + d_i
            for (int k = 0; k < pad; ++k) csr[st + k] = n;
        }
    }
}

// ---------------- gather mean-agg: explicit 2-deep pipeline, pk_add ---------
// feat: self half rows, stride 128 uints; dummy row n is zeros.
// lane = eg*16 + c; edge slot eg in [0,4), cols c*4..c*4+3 (uint4 = 16B).
__global__ __launch_bounds__(256) void gather_kernel(const unsigned int* __restrict__ feat,
                                                     const int* __restrict__ rowptrP,
                                                     const int* __restrict__ cnts,
                                                     const int* __restrict__ csr,
                                                     unsigned int* __restrict__ agg, int n) {
    int wv = (blockIdx.x * 256 + threadIdx.x) >> 6;
    if (wv >= n) return;
    int lane = threadIdx.x & 63;
    int eg = lane >> 4;
    int c4 = (lane & 15) * 4;
    int beg = rowptrP[wv];
    int deg = cnts[wv];
    int endp = beg + ((deg + 3) & ~3);
    f32x2 a0 = (f32x2)(0.f), a1 = (f32x2)(0.f), a2 = (f32x2)(0.f), a3 = (f32x2)(0.f);
    if (deg > 0) {
        // 2-deep pipeline: row load for iter k+1 and csr load for iter k+2
        // are issued before iter k's accumulate chain.
        int s0 = csr[beg + eg];
        uint4 v = *reinterpret_cast<const uint4*>(feat + (size_t)s0 * 128 + c4);
        int nx = beg + 4;
        int s1 = csr[(nx < endp ? nx : beg) + eg];
        while (nx < endp) {
            uint4 v2 = *reinterpret_cast<const uint4*>(feat + (size_t)s1 * 128 + c4);
            int nx2 = nx + 4;
            int s2 = csr[(nx2 < endp ? nx2 : beg) + eg];
            a0 += (f32x2){bflo(v.x), bfhi(v.x)};
            a1 += (f32x2){bflo(v.y), bfhi(v.y)};
            a2 += (f32x2){bflo(v.z), bfhi(v.z)};
            a3 += (f32x2){bflo(v.w), bfhi(v.w)};
            v = v2;
            s1 = s2;
            nx = nx2;
        }
        a0 += (f32x2){bflo(v.x), bfhi(v.x)};
        a1 += (f32x2){bflo(v.y), bfhi(v.y)};
        a2 += (f32x2){bflo(v.z), bfhi(v.z)};
        a3 += (f32x2){bflo(v.w), bfhi(v.w)};
    }
    float acc[8] = {a0.x, a0.y, a1.x, a1.y, a2.x, a2.y, a3.x, a3.y};
#pragma unroll
    for (int q = 0; q < 8; ++q) {
        acc[q] += __shfl_xor(acc[q], 16);
        acc[q] += __shfl_xor(acc[q], 32);
    }
    if (eg == 0) {
        float ic = 1.0f / fmaxf((float)deg, 1.0f);
        uint4 r;
        r.x = (unsigned)f2bf(acc[0] * ic) | ((unsigned)f2bf(acc[1] * ic) << 16);
        r.y = (unsigned)f2bf(acc[2] * ic) | ((unsigned)f2bf(acc[3] * ic) << 16);
        r.z = (unsigned)f2bf(acc[4] * ic) | ((unsigned)f2bf(acc[5] * ic) << 16);
        r.w = (unsigned)f2bf(acc[6] * ic) | ((unsigned)f2bf(acc[7] * ic) << 16);
        *reinterpret_cast<uint4*>(agg + (size_t)wv * 128 + c4) = r;
    }
}

// ---------------- MFMA GEMM: out = A(n x 256) @ W(256 x 128) + bias ---------
// 4 waves/block; wave owns 32 rows x 128 cols = 2x8 frags of 16x16x32.
// MODE 0: relu -> bf16 self half of A2. MODE 1: fp32 split mu/logstd.
template <int MODE>
__global__ __launch_bounds__(256) void mfma_gemm(const unsigned short* __restrict__ A,
                                                 const unsigned short* __restrict__ Bp,
                                                 const float* __restrict__ bias,
                                                 void* __restrict__ outp, int n) {
    const int tid = threadIdx.x;
    const int w = tid >> 6, l = tid & 63;
    const int lr = l & 15;
    const int lg = l >> 4;
    const int row0 = blockIdx.x * 128 + w * 32;

    f32x4 acc[2][8];
#pragma unroll
    for (int mf = 0; mf < 2; ++mf)
#pragma unroll
        for (int nf = 0; nf < 8; ++nf) acc[mf][nf] = (f32x4)(0.0f);

    int r0 = row0 + lr;       if (r0 > n - 1) r0 = n - 1;
    int r1 = row0 + 16 + lr;  if (r1 > n - 1) r1 = n - 1;
    const unsigned short* a0p = A + (size_t)r0 * 256 + lg * 8;
    const unsigned short* a1p = A + (size_t)r1 * 256 + lg * 8;
    const unsigned short* bp = Bp + (size_t)l * 8;

    for (int ks = 0; ks < 8; ++ks) {
        bf16x8 a0 = *reinterpret_cast<const bf16x8*>(a0p + ks * 32);
        bf16x8 a1 = *reinterpret_cast<const bf16x8*>(a1p + ks * 32);
#pragma unroll
        for (int nf = 0; nf < 8; ++nf) {
            bf16x8 b = *reinterpret_cast<const bf16x8*>(bp + ((nf * 8 + ks) << 9));
            acc[0][nf] = __builtin_amdgcn_mfma_f32_16x16x32_bf16(a0, b, acc[0][nf], 0, 0, 0);
            acc[1][nf] = __builtin_amdgcn_mfma_f32_16x16x32_bf16(a1, b, acc[1][nf], 0, 0, 0);
        }
    }

    float bv[8];
#pragma unroll
    for (int nf = 0; nf < 8; ++nf) bv[nf] = bias[nf * 16 + lr];

#pragma unroll
    for (int mf = 0; mf < 2; ++mf)
#pragma unroll
        for (int j = 0; j < 4; ++j) {
            int row = row0 + mf * 16 + lg * 4 + j;
            if (row >= n) continue;
#pragma unroll
            for (int nf = 0; nf < 8; ++nf) {
                int col = nf * 16 + lr;
                float v = acc[mf][nf][j] + bv[nf];
                if (MODE == 0) {
                    v = fmaxf(v, 0.0f);
                    ((unsigned short*)outp)[(size_t)row * 256 + 128 + col] = f2bf(v);
                } else {
                    float* o = (float*)outp;
                    if (col < 64) o[(size_t)row * 64 + col] = v;
                    else o[(size_t)n * 64 + (size_t)row * 64 + (col - 64)] = v;
                }
            }
        }
}

extern "C" void kernel_launch(void* const* d_in, const int* in_sizes, int n_in,
                              void* d_out, int out_size, void* d_ws, size_t ws_size,
                              hipStream_t stream) {
    const float* x = (const float*)d_in[0];
    const int* eidx_raw = (const int*)d_in[1];
    const float* W1l = (const float*)d_in[2];
    const float* b1 = (const float*)d_in[3];
    const float* W1r = (const float*)d_in[4];
    const float* Wml = (const float*)d_in[5];
    const float* bm = (const float*)d_in[6];
    const float* Wmr = (const float*)d_in[7];
    const float* Wsl = (const float*)d_in[8];
    const float* bs = (const float*)d_in[9];
    const float* Wsr = (const float*)d_in[10];
    float* out = (float*)d_out;

    const int n = in_sizes[0] / 128;   // 100000 (<= 131072)
    const int nE = in_sizes[1] / 2;    // 1600000

    const int NB = ((n - 1) >> SHIFT) + 1;  // 196
    long long capll = (((long long)nE << SHIFT) / n) * 5 / 4 + 1024;
    const int cap = (int)((capll + 15) & ~15LL);
    const int csr_ints = nE + NB * 3 * BW + 64;

    // ---- workspace layout (bytes); A1/A2 have n+1 rows (row n = zero dummy).
    // recs (~9MB) overlays A2 rows < n (dead before mfma_gemm<0> writes A2;
    // A2 row n at offset n*512 is beyond the recs region).
    char* ws = (char*)d_ws;
    const size_t a_bytes = (size_t)(n + 1) * 512;
    const size_t a1_off = 0;
    const size_t a2_off = a1_off + a_bytes;
    const size_t recs_off = a2_off;
    const size_t csr_off = a2_off + a_bytes;
    const size_t rowptr_off = csr_off + (size_t)csr_ints * 4;   // n ints
    const size_t cnts_off = rowptr_off + (size_t)n * 4;         // n ints
    const size_t bcnt_off = cnts_off + (size_t)n * 4;           // 256 ints
    const size_t b1p_off = (bcnt_off + 1024 + 255) & ~(size_t)255;
    const size_t b2p_off = b1p_off + 65536;
    const size_t bc_off = b2p_off + 65536;

    unsigned short* A1 = (unsigned short*)(ws + a1_off);
    unsigned short* A2 = (unsigned short*)(ws + a2_off);
    unsigned* recs = (unsigned*)(ws + recs_off);
    int* csr = (int*)(ws + csr_off);
    int* rowptrP = (int*)(ws + rowptr_off);
    int* cnts = (int*)(ws + cnts_off);
    int* bcnt = (int*)(ws + bcnt_off);
    unsigned short* B1p = (unsigned short*)(ws + b1p_off);
    unsigned short* B2p = (unsigned short*)(ws + b2p_off);
    float* bc = (float*)(ws + bc_off);

    hipMemsetAsync(bcnt, 0, 1024, stream);

    // stage1: binA (critical path, scheduled first) + xcvt + pack + zero
    const int nBinA = (nE + 4095) / 4096;
    const int nXB = (n * 32 + 255) / 256;  // xcvt blocks (4 floats/thread)
    stage1_kernel<<<nBinA + nXB + 129, 256, 0, stream>>>(
        x, eidx_raw, W1l, W1r, Wml, Wmr, Wsl, Wsr, bm, bs,
        B1p, B2p, bc, A1, A2, bcnt, recs, n, nE, cap, nBinA, nXB);

    // CSR build phase B (padded)
    binB_kernel<<<NB, 256, 0, stream>>>(recs, bcnt, rowptrP, cnts, csr, cap, n, NB);

    const int gather_blocks = (n * 64 + 255) / 256;
    const int gemm_blocks = (n + 127) / 128;

    // layer 1
    gather_kernel<<<gather_blocks, 256, 0, stream>>>(
        (const unsigned int*)A1 + 64, rowptrP, cnts, csr, (unsigned int*)A1, n);
    mfma_gemm<0><<<gemm_blocks, 256, 0, stream>>>(A1, B1p, b1, A2, n);

    // layer 2 (fused mu/logstd heads)
    gather_kernel<<<gather_blocks, 256, 0, stream>>>(
        (const unsigned int*)A2 + 64, rowptrP, cnts, csr, (unsigned int*)A2, n);
    mfma_gemm<1><<<gemm_blocks, 256, 0, stream>>>(A2, B2p, bc, out, n);
}